// Round 1
// baseline (692.561 us; speedup 1.0000x reference)
//
#include <hip/hip_runtime.h>
#include <math.h>

// Problem constants (UnifiedMambaBlock, B=1)
#define L      4096
#define DM     768
#define DI     1536
#define DS     16
#define DR     48
#define NCOMB  80     // 48 dt_rank + 16 B + 16 C
#define CH     64     // scan chunk length
#define NC     64     // number of chunks (L / CH)

__device__ __forceinline__ float silu_f(float v) { return v / (1.f + __expf(-v)); }

// ---------------------------------------------------------------------------
// Generic fp32 GEMM:  C[M,N] = A[M,K(lda)] @ W[N,K]^T   (+ optional epilogue)
// EPI 0: plain store. EPI 1: softplus(acc + bias[col])
// 64x64 tile, BK=16, 256 threads, 4x4 per thread.
// ---------------------------------------------------------------------------
template <int EPI>
__global__ __launch_bounds__(256)
void gemm_f32(const float* __restrict__ A, int lda,
              const float* __restrict__ W,
              const float* __restrict__ bias,
              float* __restrict__ C,
              int M, int N, int K)
{
    __shared__ float As[16][64];
    __shared__ float Ws[16][64];

    const int tid = threadIdx.x;
    const int tx = tid & 15;        // col group
    const int ty = tid >> 4;        // row group
    const int m0 = blockIdx.y * 64;
    const int n0 = blockIdx.x * 64;

    const int lrow = tid >> 2;          // 0..63
    const int lk   = (tid & 3) * 4;     // 0,4,8,12

    float acc[4][4] = {{0.f}};

    for (int kk = 0; kk < K; kk += 16) {
        // stage A tile (rows m0..m0+63, k kk..kk+15), k-major in LDS
        {
            const float4 v = *(const float4*)(A + (size_t)(m0 + lrow) * lda + kk + lk);
            As[lk + 0][lrow] = v.x; As[lk + 1][lrow] = v.y;
            As[lk + 2][lrow] = v.z; As[lk + 3][lrow] = v.w;
        }
        // stage W tile (rows n0..n0+63 of W, masked for N not multiple of 64)
        {
            float4 v = make_float4(0.f, 0.f, 0.f, 0.f);
            if (n0 + lrow < N)
                v = *(const float4*)(W + (size_t)(n0 + lrow) * K + kk + lk);
            Ws[lk + 0][lrow] = v.x; Ws[lk + 1][lrow] = v.y;
            Ws[lk + 2][lrow] = v.z; Ws[lk + 3][lrow] = v.w;
        }
        __syncthreads();

        #pragma unroll
        for (int k = 0; k < 16; ++k) {
            const float4 av = *(const float4*)&As[k][ty * 4];
            const float4 bv = *(const float4*)&Ws[k][tx * 4];
            const float a[4] = {av.x, av.y, av.z, av.w};
            const float b[4] = {bv.x, bv.y, bv.z, bv.w};
            #pragma unroll
            for (int i = 0; i < 4; ++i)
                #pragma unroll
                for (int j = 0; j < 4; ++j)
                    acc[i][j] = fmaf(a[i], b[j], acc[i][j]);
        }
        __syncthreads();
    }

    const int col = n0 + tx * 4;
    if (col < N) {   // N is always a multiple of 4 here, so float4 granularity is safe
        #pragma unroll
        for (int i = 0; i < 4; ++i) {
            const int row = m0 + ty * 4 + i;
            float4 v;
            float r[4];
            #pragma unroll
            for (int j = 0; j < 4; ++j) {
                float x = acc[i][j];
                if (EPI == 1) {
                    x += bias[col + j];
                    x = (x > 20.f) ? x : log1pf(expf(x));   // softplus
                }
                r[j] = x;
            }
            v.x = r[0]; v.y = r[1]; v.z = r[2]; v.w = r[3];
            *(float4*)(C + (size_t)row * N + col) = v;
        }
    }
}

// ---------------------------------------------------------------------------
// Pack [x_dt_w(48); x_b_w(16); x_c_w(16)] -> Wc[80][1536]
// ---------------------------------------------------------------------------
__global__ void pack_wc_k(const float* __restrict__ xdt, const float* __restrict__ xb,
                          const float* __restrict__ xc, float* __restrict__ Wc)
{
    int i = blockIdx.x * 256 + threadIdx.x;
    if (i >= NCOMB * DI) return;
    int r = i / DI, c = i - r * DI;
    float v;
    if (r < 48)      v = xdt[r * DI + c];
    else if (r < 64) v = xb[(r - 48) * DI + c];
    else             v = xc[(r - 64) * DI + c];
    Wc[i] = v;
}

// ---------------------------------------------------------------------------
// Causal depthwise conv (width 4) + bias + SiLU.  x = xz[:, :DI]
// ---------------------------------------------------------------------------
__global__ __launch_bounds__(256)
void conv_silu_k(const float* __restrict__ xz, const float* __restrict__ cw,
                 const float* __restrict__ cb, float* __restrict__ xcv)
{
    int idx = blockIdx.x * 256 + threadIdx.x;
    if (idx >= L * DI) return;
    int t = idx / DI, d = idx - t * DI;
    const float4 w = *(const float4*)(cw + d * 4);
    const float* xcol = xz + d;
    float acc = cb[d];
    if (t >= 3) acc = fmaf(w.x, xcol[(size_t)(t - 3) * (2 * DI)], acc);
    if (t >= 2) acc = fmaf(w.y, xcol[(size_t)(t - 2) * (2 * DI)], acc);
    if (t >= 1) acc = fmaf(w.z, xcol[(size_t)(t - 1) * (2 * DI)], acc);
    acc = fmaf(w.w, xcol[(size_t)t * (2 * DI)], acc);
    xcv[idx] = silu_f(acc);
}

// ---------------------------------------------------------------------------
// Scan pass 1: per chunk c, per channel d: local state h[16] (zero init) and
// S = sum(dt) over chunk.  Thread = (c, d); h,A in registers; B staged in LDS.
// ---------------------------------------------------------------------------
__global__ __launch_bounds__(256)
void scan1_k(const float* __restrict__ dt, const float* __restrict__ xcv,
             const float* __restrict__ dtbc, const float* __restrict__ alog,
             float* __restrict__ hloc, float* __restrict__ Ssum)
{
    __shared__ float Bs[CH][DS];
    const int c = blockIdx.y;
    const int d = blockIdx.x * 256 + threadIdx.x;

    for (int i = threadIdx.x; i < CH * DS; i += 256) {
        int tt = i >> 4, n = i & 15;
        Bs[tt][n] = dtbc[(size_t)(c * CH + tt) * NCOMB + 48 + n];
    }
    __syncthreads();

    float Ad[DS], h[DS];
    #pragma unroll
    for (int n = 0; n < DS; ++n) {
        Ad[n] = -expf(alog[d * DS + n]);
        h[n] = 0.f;
    }

    size_t base = (size_t)(c * CH) * DI + d;
    float S = 0.f;
    for (int tt = 0; tt < CH; ++tt, base += DI) {
        const float dtv = dt[base];
        const float xv  = xcv[base];
        S += dtv;
        const float xdt = xv * dtv;
        #pragma unroll
        for (int n = 0; n < DS; ++n)
            h[n] = fmaf(h[n], __expf(Ad[n] * dtv), xdt * Bs[tt][n]);
    }

    const size_t o = ((size_t)c * DI + d) * DS;
    #pragma unroll
    for (int n = 0; n < DS; ++n) hloc[o + n] = h[n];
    Ssum[c * DI + d] = S;
}

// ---------------------------------------------------------------------------
// Scan pass 2: sequential scan over the 64 chunk carries, one thread per
// (d,n) pair.  hc is hloc on input, carry on output (in-place, read-first).
// ---------------------------------------------------------------------------
__global__ __launch_bounds__(256)
void scan2_k(float* hc, const float* __restrict__ Ssum,
             const float* __restrict__ alog)
{
    const int p = blockIdx.x * 256 + threadIdx.x;   // [0, DI*DS)
    if (p >= DI * DS) return;
    const int d = p >> 4;
    const float Ad = -expf(alog[p]);
    float h = 0.f;
    for (int c = 0; c < NC; ++c) {
        const size_t o = (size_t)c * DI * DS + p;
        const float hl = hc[o];      // read local state first
        hc[o] = h;                   // overwrite with carry-in
        h = fmaf(h, __expf(Ad * Ssum[c * DI + d]), hl);
    }
}

// ---------------------------------------------------------------------------
// Scan pass 3: replay chunk with carry-in, emit yz = (y_ssm) * silu(z).
// dty serves as dt input AND yz output (each element read once, then written).
// ---------------------------------------------------------------------------
__global__ __launch_bounds__(256)
void scan3_k(float* dty, const float* __restrict__ xcv,
             const float* __restrict__ dtbc, const float* __restrict__ alog,
             const float* __restrict__ carry, const float* __restrict__ Dp,
             const float* __restrict__ xz)
{
    __shared__ float Bs[CH][DS];
    __shared__ float Cs[CH][DS];
    const int c = blockIdx.y;
    const int d = blockIdx.x * 256 + threadIdx.x;

    for (int i = threadIdx.x; i < CH * DS; i += 256) {
        int tt = i >> 4, n = i & 15;
        Bs[tt][n] = dtbc[(size_t)(c * CH + tt) * NCOMB + 48 + n];
        Cs[tt][n] = dtbc[(size_t)(c * CH + tt) * NCOMB + 64 + n];
    }
    __syncthreads();

    float Ad[DS], h[DS];
    const size_t co = ((size_t)c * DI + d) * DS;
    #pragma unroll
    for (int n = 0; n < DS; ++n) {
        Ad[n] = -expf(alog[d * DS + n]);
        h[n] = carry[co + n];
    }
    const float Dv = Dp[d];

    int t = c * CH;
    for (int tt = 0; tt < CH; ++tt, ++t) {
        const size_t o = (size_t)t * DI + d;
        const float dtv = dty[o];
        const float xv  = xcv[o];
        const float xdt = xv * dtv;
        float y = Dv * xv;
        #pragma unroll
        for (int n = 0; n < DS; ++n) {
            h[n] = fmaf(h[n], __expf(Ad[n] * dtv), xdt * Bs[tt][n]);
            y = fmaf(h[n], Cs[tt][n], y);
        }
        const float z = xz[(size_t)t * (2 * DI) + DI + d];
        dty[o] = y * silu_f(z);
    }
}

// ---------------------------------------------------------------------------
extern "C" void kernel_launch(void* const* d_in, const int* in_sizes, int n_in,
                              void* d_out, int out_size, void* d_ws, size_t ws_size,
                              hipStream_t stream)
{
    const float* u    = (const float*)d_in[0];
    const float* Wip  = (const float*)d_in[1];
    const float* cw   = (const float*)d_in[2];
    const float* cb   = (const float*)d_in[3];
    const float* xdt  = (const float*)d_in[4];
    const float* xbw  = (const float*)d_in[5];
    const float* xcw  = (const float*)d_in[6];
    const float* dtw  = (const float*)d_in[7];
    const float* dtb  = (const float*)d_in[8];
    const float* alog = (const float*)d_in[9];
    const float* Dp   = (const float*)d_in[10];
    const float* Wop  = (const float*)d_in[11];
    float* out = (float*)d_out;

    // workspace layout (floats) — ~109 MB total
    float* ws   = (float*)d_ws;
    float* xz   = ws;                                // L*2*DI = 12,582,912
    float* xcv  = xz   + (size_t)L * 2 * DI;         // L*DI   =  6,291,456
    float* dtbc = xcv  + (size_t)L * DI;             // L*80   =    327,680
    float* dty  = dtbc + (size_t)L * NCOMB;          // L*DI   =  6,291,456 (dt, then yz)
    float* Wc   = dty  + (size_t)L * DI;             // 80*DI  =    122,880
    float* hc   = Wc   + (size_t)NCOMB * DI;         // NC*DI*DS = 1,572,864
    float* Ssum = hc   + (size_t)NC * DI * DS;       // NC*DI  =     98,304

    const dim3 blk(256);

    // 1) xz = u @ in_proj_w^T        [4096, 3072]
    gemm_f32<0><<<dim3((2 * DI) / 64, L / 64), blk, 0, stream>>>(
        u, DM, Wip, nullptr, xz, L, 2 * DI, DM);

    // 2) pack combined projection weights  Wc[80][1536]
    pack_wc_k<<<(NCOMB * DI + 255) / 256, blk, 0, stream>>>(xdt, xbw, xcw, Wc);

    // 3) causal depthwise conv + SiLU -> x_conv
    conv_silu_k<<<(L * DI + 255) / 256, blk, 0, stream>>>(xz, cw, cb, xcv);

    // 4) [dt_rank | B | C] = x_conv @ Wc^T   [4096, 80]
    gemm_f32<0><<<dim3(2, L / 64), blk, 0, stream>>>(
        xcv, DI, Wc, nullptr, dtbc, L, NCOMB, DI);

    // 5) dt = softplus(dt_rank @ dt_w^T + dt_b)   [4096, 1536]
    gemm_f32<1><<<dim3(DI / 64, L / 64), blk, 0, stream>>>(
        dtbc, NCOMB, dtw, dtb, dty, L, DI, DR);

    // 6-8) chunked selective scan -> yz = y_ssm * silu(z)  (written into dty)
    scan1_k<<<dim3(DI / 256, NC), blk, 0, stream>>>(dty, xcv, dtbc, alog, hc, Ssum);
    scan2_k<<<(DI * DS) / 256, blk, 0, stream>>>(hc, Ssum, alog);
    scan3_k<<<dim3(DI / 256, NC), blk, 0, stream>>>(dty, xcv, dtbc, alog, hc, Dp, xz);

    // 9) out = yz @ out_proj_w^T   [4096, 768]
    gemm_f32<0><<<dim3(DM / 64, L / 64), blk, 0, stream>>>(
        dty, DI, Wop, nullptr, out, L, DM, DI);
}

// Round 2
// 384.561 us; speedup vs baseline: 1.8009x; 1.8009x over previous
//
#include <hip/hip_runtime.h>
#include <math.h>

// Problem constants (UnifiedMambaBlock, B=1)
#define L      4096
#define DM     768
#define DI     1536
#define DS     16
#define DR     48
#define NCOMB  80     // 48 dt_rank + 16 B + 16 C
#define CH     64     // scan chunk length
#define NC     64     // number of chunks (L / CH)

typedef unsigned short u16;
typedef unsigned int   u32;
typedef __attribute__((ext_vector_type(8))) short bf16x8;   // 8 bf16 = 4 VGPRs
typedef __attribute__((ext_vector_type(4))) float f32x4;

__device__ __forceinline__ float silu_f(float v) { return v / (1.f + __expf(-v)); }

__device__ __forceinline__ u16 f2bf(float f) {              // RNE f32 -> bf16
    u32 u = __float_as_uint(f);
    return (u16)((u + 0x7fffu + ((u >> 16) & 1u)) >> 16);
}
__device__ __forceinline__ float bf2f(u16 h) {
    return __uint_as_float(((u32)h) << 16);
}

__device__ __forceinline__ void gl_lds16(const u16* g, u16* l) {
    __builtin_amdgcn_global_load_lds(
        (const __attribute__((address_space(1))) void*)g,
        (__attribute__((address_space(3))) void*)l, 16, 0, 0);
}

// ---------------------------------------------------------------------------
// bf16 MFMA GEMM (m97 structure): C[M,N] fp32 = A[M,K] @ W[N,K]^T, bf16 in.
// 128x128 tile, BK=32, 256 threads (4 waves, 2x2 of 64x64), double-buffer LDS,
// global_load_lds width=16.  M,N multiples of 128; K multiple of 32.
// ---------------------------------------------------------------------------
__global__ __launch_bounds__(256)
void gemm_bf16_bt(const u16* __restrict__ A, const u16* __restrict__ W,
                  float* __restrict__ C, int M, int N, int K)
{
    __shared__ u16 As[2][128 * 32];
    __shared__ u16 Bs[2][128 * 32];

    const int tid  = threadIdx.x;
    const int lane = tid & 63;
    const int wave = tid >> 6;                 // 0..3
    const int wr   = (wave >> 1) * 64;         // wave row offset in tile
    const int wc   = (wave & 1) * 64;          // wave col offset in tile
    const int m0   = blockIdx.y * 128;
    const int n0   = blockIdx.x * 128;

    // staging mapping: 16B chunk j*256+tid -> row (j*64 + tid/4), k (tid%4)*8
    const int r0 = tid >> 2;
    const int k0 = (tid & 3) * 8;

    // fragment mapping (16x16x32): row/col = lane&15, kbase = (lane>>4)*8
    const int frow = lane & 15;
    const int fk   = (lane >> 4) * 8;

    f32x4 acc[4][4];
    #pragma unroll
    for (int i = 0; i < 4; ++i)
        #pragma unroll
        for (int j = 0; j < 4; ++j)
            acc[i][j] = (f32x4){0.f, 0.f, 0.f, 0.f};

    const int NT = K >> 5;

#define STAGE(buf, kk) {                                                       \
        const u16* ga = A + (size_t)(m0 + r0) * K + (kk) + k0;                 \
        const u16* gw = W + (size_t)(n0 + r0) * K + (kk) + k0;                 \
        gl_lds16(ga,                   &As[buf][tid * 8]);                     \
        gl_lds16(ga + (size_t)64 * K,  &As[buf][2048 + tid * 8]);              \
        gl_lds16(gw,                   &Bs[buf][tid * 8]);                     \
        gl_lds16(gw + (size_t)64 * K,  &Bs[buf][2048 + tid * 8]); }

    STAGE(0, 0);
    __syncthreads();

    for (int t = 0; t < NT; ++t) {
        const int b = t & 1;
        if (t + 1 < NT) STAGE(b ^ 1, (t + 1) << 5);

        bf16x8 af[4], bw[4];
        #pragma unroll
        for (int m = 0; m < 4; ++m)
            af[m] = *(const bf16x8*)&As[b][(wr + m * 16 + frow) * 32 + fk];
        #pragma unroll
        for (int n = 0; n < 4; ++n)
            bw[n] = *(const bf16x8*)&Bs[b][(wc + n * 16 + frow) * 32 + fk];

        #pragma unroll
        for (int m = 0; m < 4; ++m)
            #pragma unroll
            for (int n = 0; n < 4; ++n)
                acc[m][n] = __builtin_amdgcn_mfma_f32_16x16x32_bf16(
                    af[m], bw[n], acc[m][n], 0, 0, 0);

        __syncthreads();
    }
#undef STAGE

    // C/D layout: col = lane&15, row = (lane>>4)*4 + reg   [m89-verified]
    const int crow = (lane >> 4) * 4;
    const int ccol = lane & 15;
    #pragma unroll
    for (int m = 0; m < 4; ++m)
        #pragma unroll
        for (int n = 0; n < 4; ++n)
            #pragma unroll
            for (int r = 0; r < 4; ++r)
                C[(size_t)(m0 + wr + m * 16 + crow + r) * N
                  + n0 + wc + n * 16 + ccol] = acc[m][n][r];
}

// ---------------------------------------------------------------------------
// split-3 pack: fp32 [M][K] -> bf16 [M][3K] as [hi | lo | hi]
// (pairs with weight pack [hi | hi | lo] to give fp32-grade bf16 MFMA GEMM)
// ---------------------------------------------------------------------------
__global__ __launch_bounds__(256)
void pack_split3_k(const float* __restrict__ in, u16* __restrict__ out,
                   int MK4, int K)
{
    int i = blockIdx.x * 256 + threadIdx.x;
    if (i >= MK4) return;
    const float4 v = ((const float4*)in)[i];
    const int e = i * 4;
    const int r = e / K, c = e - r * K;
    const float f[4] = {v.x, v.y, v.z, v.w};
    ushort4 hi, lo;
    u16 h, l;
    h = f2bf(f[0]); l = f2bf(f[0] - bf2f(h)); hi.x = h; lo.x = l;
    h = f2bf(f[1]); l = f2bf(f[1] - bf2f(h)); hi.y = h; lo.y = l;
    h = f2bf(f[2]); l = f2bf(f[2] - bf2f(h)); hi.z = h; lo.z = l;
    h = f2bf(f[3]); l = f2bf(f[3] - bf2f(h)); hi.w = h; lo.w = l;
    u16* row = out + (size_t)r * 3 * K + c;
    *(ushort4*)(row)         = hi;
    *(ushort4*)(row + K)     = lo;
    *(ushort4*)(row + 2 * K) = hi;
}

// weight variant: [hi | hi | lo]
__global__ __launch_bounds__(256)
void pack_split3w_k(const float* __restrict__ in, u16* __restrict__ out,
                    int MK4, int K)
{
    int i = blockIdx.x * 256 + threadIdx.x;
    if (i >= MK4) return;
    const float4 v = ((const float4*)in)[i];
    const int e = i * 4;
    const int r = e / K, c = e - r * K;
    const float f[4] = {v.x, v.y, v.z, v.w};
    ushort4 hi, lo;
    u16 h, l;
    h = f2bf(f[0]); l = f2bf(f[0] - bf2f(h)); hi.x = h; lo.x = l;
    h = f2bf(f[1]); l = f2bf(f[1] - bf2f(h)); hi.y = h; lo.y = l;
    h = f2bf(f[2]); l = f2bf(f[2] - bf2f(h)); hi.z = h; lo.z = l;
    h = f2bf(f[3]); l = f2bf(f[3] - bf2f(h)); hi.w = h; lo.w = l;
    u16* row = out + (size_t)r * 3 * K + c;
    *(ushort4*)(row)         = hi;
    *(ushort4*)(row + K)     = hi;
    *(ushort4*)(row + 2 * K) = lo;
}

// plain fp32 -> bf16 pack
__global__ __launch_bounds__(256)
void pack_bf16_k(const float* __restrict__ in, u16* __restrict__ out, int N4)
{
    int i = blockIdx.x * 256 + threadIdx.x;
    if (i >= N4) return;
    const float4 v = ((const float4*)in)[i];
    ushort4 o;
    o.x = f2bf(v.x); o.y = f2bf(v.y); o.z = f2bf(v.z); o.w = f2bf(v.w);
    ((ushort4*)out)[i] = o;
}

// ---------------------------------------------------------------------------
// Generic fp32 GEMM (kept for the small GEMMs 2 & 3)
// EPI 0: plain store. EPI 1: softplus(acc + bias[col])
// ---------------------------------------------------------------------------
template <int EPI>
__global__ __launch_bounds__(256)
void gemm_f32(const float* __restrict__ A, int lda,
              const float* __restrict__ W,
              const float* __restrict__ bias,
              float* __restrict__ C,
              int M, int N, int K)
{
    __shared__ float As[16][64];
    __shared__ float Ws[16][64];

    const int tid = threadIdx.x;
    const int tx = tid & 15;
    const int ty = tid >> 4;
    const int m0 = blockIdx.y * 64;
    const int n0 = blockIdx.x * 64;

    const int lrow = tid >> 2;
    const int lk   = (tid & 3) * 4;

    float acc[4][4] = {{0.f}};

    for (int kk = 0; kk < K; kk += 16) {
        {
            const float4 v = *(const float4*)(A + (size_t)(m0 + lrow) * lda + kk + lk);
            As[lk + 0][lrow] = v.x; As[lk + 1][lrow] = v.y;
            As[lk + 2][lrow] = v.z; As[lk + 3][lrow] = v.w;
        }
        {
            float4 v = make_float4(0.f, 0.f, 0.f, 0.f);
            if (n0 + lrow < N)
                v = *(const float4*)(W + (size_t)(n0 + lrow) * K + kk + lk);
            Ws[lk + 0][lrow] = v.x; Ws[lk + 1][lrow] = v.y;
            Ws[lk + 2][lrow] = v.z; Ws[lk + 3][lrow] = v.w;
        }
        __syncthreads();

        #pragma unroll
        for (int k = 0; k < 16; ++k) {
            const float4 av = *(const float4*)&As[k][ty * 4];
            const float4 bv = *(const float4*)&Ws[k][tx * 4];
            const float a[4] = {av.x, av.y, av.z, av.w};
            const float b[4] = {bv.x, bv.y, bv.z, bv.w};
            #pragma unroll
            for (int i = 0; i < 4; ++i)
                #pragma unroll
                for (int j = 0; j < 4; ++j)
                    acc[i][j] = fmaf(a[i], b[j], acc[i][j]);
        }
        __syncthreads();
    }

    const int col = n0 + tx * 4;
    if (col < N) {
        #pragma unroll
        for (int i = 0; i < 4; ++i) {
            const int row = m0 + ty * 4 + i;
            float4 v;
            float r[4];
            #pragma unroll
            for (int j = 0; j < 4; ++j) {
                float x = acc[i][j];
                if (EPI == 1) {
                    x += bias[col + j];
                    x = (x > 20.f) ? x : log1pf(expf(x));
                }
                r[j] = x;
            }
            v.x = r[0]; v.y = r[1]; v.z = r[2]; v.w = r[3];
            *(float4*)(C + (size_t)row * N + col) = v;
        }
    }
}

// ---------------------------------------------------------------------------
__global__ void pack_wc_k(const float* __restrict__ xdt, const float* __restrict__ xb,
                          const float* __restrict__ xc, float* __restrict__ Wc)
{
    int i = blockIdx.x * 256 + threadIdx.x;
    if (i >= NCOMB * DI) return;
    int r = i / DI, c = i - r * DI;
    float v;
    if (r < 48)      v = xdt[r * DI + c];
    else if (r < 64) v = xb[(r - 48) * DI + c];
    else             v = xc[(r - 64) * DI + c];
    Wc[i] = v;
}

__global__ __launch_bounds__(256)
void conv_silu_k(const float* __restrict__ xz, const float* __restrict__ cw,
                 const float* __restrict__ cb, float* __restrict__ xcv)
{
    int idx = blockIdx.x * 256 + threadIdx.x;
    if (idx >= L * DI) return;
    int t = idx / DI, d = idx - t * DI;
    const float4 w = *(const float4*)(cw + d * 4);
    const float* xcol = xz + d;
    float acc = cb[d];
    if (t >= 3) acc = fmaf(w.x, xcol[(size_t)(t - 3) * (2 * DI)], acc);
    if (t >= 2) acc = fmaf(w.y, xcol[(size_t)(t - 2) * (2 * DI)], acc);
    if (t >= 1) acc = fmaf(w.z, xcol[(size_t)(t - 1) * (2 * DI)], acc);
    acc = fmaf(w.w, xcol[(size_t)t * (2 * DI)], acc);
    xcv[idx] = silu_f(acc);
}

__global__ __launch_bounds__(256)
void scan1_k(const float* __restrict__ dt, const float* __restrict__ xcv,
             const float* __restrict__ dtbc, const float* __restrict__ alog,
             float* __restrict__ hloc, float* __restrict__ Ssum)
{
    __shared__ float Bs[CH][DS];
    const int c = blockIdx.y;
    const int d = blockIdx.x * 256 + threadIdx.x;

    for (int i = threadIdx.x; i < CH * DS; i += 256) {
        int tt = i >> 4, n = i & 15;
        Bs[tt][n] = dtbc[(size_t)(c * CH + tt) * NCOMB + 48 + n];
    }
    __syncthreads();

    float Ad[DS], h[DS];
    #pragma unroll
    for (int n = 0; n < DS; ++n) {
        Ad[n] = -expf(alog[d * DS + n]);
        h[n] = 0.f;
    }

    size_t base = (size_t)(c * CH) * DI + d;
    float S = 0.f;
    for (int tt = 0; tt < CH; ++tt, base += DI) {
        const float dtv = dt[base];
        const float xv  = xcv[base];
        S += dtv;
        const float xdt = xv * dtv;
        #pragma unroll
        for (int n = 0; n < DS; ++n)
            h[n] = fmaf(h[n], __expf(Ad[n] * dtv), xdt * Bs[tt][n]);
    }

    const size_t o = ((size_t)c * DI + d) * DS;
    #pragma unroll
    for (int n = 0; n < DS; ++n) hloc[o + n] = h[n];
    Ssum[c * DI + d] = S;
}

__global__ __launch_bounds__(256)
void scan2_k(float* hc, const float* __restrict__ Ssum,
             const float* __restrict__ alog)
{
    const int p = blockIdx.x * 256 + threadIdx.x;
    if (p >= DI * DS) return;
    const int d = p >> 4;
    const float Ad = -expf(alog[p]);
    float h = 0.f;
    for (int c = 0; c < NC; ++c) {
        const size_t o = (size_t)c * DI * DS + p;
        const float hl = hc[o];
        hc[o] = h;
        h = fmaf(h, __expf(Ad * Ssum[c * DI + d]), hl);
    }
}

__global__ __launch_bounds__(256)
void scan3_k(float* dty, const float* __restrict__ xcv,
             const float* __restrict__ dtbc, const float* __restrict__ alog,
             const float* __restrict__ carry, const float* __restrict__ Dp,
             const float* __restrict__ xz)
{
    __shared__ float Bs[CH][DS];
    __shared__ float Cs[CH][DS];
    const int c = blockIdx.y;
    const int d = blockIdx.x * 256 + threadIdx.x;

    for (int i = threadIdx.x; i < CH * DS; i += 256) {
        int tt = i >> 4, n = i & 15;
        Bs[tt][n] = dtbc[(size_t)(c * CH + tt) * NCOMB + 48 + n];
        Cs[tt][n] = dtbc[(size_t)(c * CH + tt) * NCOMB + 64 + n];
    }
    __syncthreads();

    float Ad[DS], h[DS];
    const size_t co = ((size_t)c * DI + d) * DS;
    #pragma unroll
    for (int n = 0; n < DS; ++n) {
        Ad[n] = -expf(alog[d * DS + n]);
        h[n] = carry[co + n];
    }
    const float Dv = Dp[d];

    int t = c * CH;
    for (int tt = 0; tt < CH; ++tt, ++t) {
        const size_t o = (size_t)t * DI + d;
        const float dtv = dty[o];
        const float xv  = xcv[o];
        const float xdt = xv * dtv;
        float y = Dv * xv;
        #pragma unroll
        for (int n = 0; n < DS; ++n) {
            h[n] = fmaf(h[n], __expf(Ad[n] * dtv), xdt * Bs[tt][n]);
            y = fmaf(h[n], Cs[tt][n], y);
        }
        const float z = xz[(size_t)t * (2 * DI) + DI + d];
        dty[o] = y * silu_f(z);
    }
}

// ---------------------------------------------------------------------------
extern "C" void kernel_launch(void* const* d_in, const int* in_sizes, int n_in,
                              void* d_out, int out_size, void* d_ws, size_t ws_size,
                              hipStream_t stream)
{
    const float* u    = (const float*)d_in[0];
    const float* Wip  = (const float*)d_in[1];
    const float* cw   = (const float*)d_in[2];
    const float* cb   = (const float*)d_in[3];
    const float* xdt  = (const float*)d_in[4];
    const float* xbw  = (const float*)d_in[5];
    const float* xcw  = (const float*)d_in[6];
    const float* dtw  = (const float*)d_in[7];
    const float* dtb  = (const float*)d_in[8];
    const float* alog = (const float*)d_in[9];
    const float* Dp   = (const float*)d_in[10];
    const float* Wop  = (const float*)d_in[11];
    float* out = (float*)d_out;

    // workspace layout (floats) — same 109 MB footprint as round 1
    float* ws   = (float*)d_ws;
    float* xz   = ws;                                // L*2*DI
    float* xcv  = xz   + (size_t)L * 2 * DI;         // L*DI
    float* dtbc = xcv  + (size_t)L * DI;             // L*NCOMB
    float* dty  = dtbc + (size_t)L * NCOMB;          // L*DI
    float* Wc   = dty  + (size_t)L * DI;             // NCOMB*DI
    float* hc   = Wc   + (size_t)NCOMB * DI;         // NC*DI*DS
    float* Ssum = hc   + (size_t)NC * DI * DS;       // NC*DI

    // bf16 aliases into regions that are dead at the time of use:
    u16* u3   = (u16*)xcv;                 // [4096][2304] bf16, dead after GEMM1
    u16* W3   = (u16*)dty;                 // [3072][2304] bf16, dead after GEMM1
    u16* ybf  = (u16*)xz;                  // [4096][1536] bf16 (xz dead after scan3)
    u16* wopb = (u16*)xz + (size_t)L * DI; // [768][1536] bf16

    const dim3 blk(256);

    // 1) split-3 packs for GEMM1
    pack_split3_k<<<(L * DM / 4 + 255) / 256, blk, 0, stream>>>(u, u3, L * DM / 4, DM);
    pack_split3w_k<<<(2 * DI * DM / 4 + 255) / 256, blk, 0, stream>>>(Wip, W3, 2 * DI * DM / 4, DM);

    // 2) xz = u @ in_proj_w^T   [4096, 3072]  (bf16 MFMA, K'=3*768)
    gemm_bf16_bt<<<dim3((2 * DI) / 128, L / 128), blk, 0, stream>>>(
        u3, W3, xz, L, 2 * DI, 3 * DM);

    // 3) pack combined projection weights  Wc[80][1536]
    pack_wc_k<<<(NCOMB * DI + 255) / 256, blk, 0, stream>>>(xdt, xbw, xcw, Wc);

    // 4) causal depthwise conv + SiLU -> x_conv  (overwrites u3 region)
    conv_silu_k<<<(L * DI + 255) / 256, blk, 0, stream>>>(xz, cw, cb, xcv);

    // 5) [dt_rank | B | C] = x_conv @ Wc^T   [4096, 80]
    gemm_f32<0><<<dim3(2, L / 64), blk, 0, stream>>>(
        xcv, DI, Wc, nullptr, dtbc, L, NCOMB, DI);

    // 6) dt = softplus(dt_rank @ dt_w^T + dt_b)  [4096, 1536] (overwrites W3)
    gemm_f32<1><<<dim3(DI / 64, L / 64), blk, 0, stream>>>(
        dtbc, NCOMB, dtw, dtb, dty, L, DI, DR);

    // 7-9) chunked selective scan -> yz (in dty)
    scan1_k<<<dim3(DI / 256, NC), blk, 0, stream>>>(dty, xcv, dtbc, alog, hc, Ssum);
    scan2_k<<<(DI * DS) / 256, blk, 0, stream>>>(hc, Ssum, alog);
    scan3_k<<<dim3(DI / 256, NC), blk, 0, stream>>>(dty, xcv, dtbc, alog, hc, Dp, xz);

    // 10) bf16 packs for GEMM4 (xz region is dead now)
    pack_bf16_k<<<(L * DI / 4 + 255) / 256, blk, 0, stream>>>(dty, ybf, L * DI / 4);
    pack_bf16_k<<<(DM * DI / 4 + 255) / 256, blk, 0, stream>>>(Wop, wopb, DM * DI / 4);

    // 11) out = yz @ out_proj_w^T   [4096, 768]  (plain bf16 MFMA)
    gemm_bf16_bt<<<dim3(DM / 128, L / 128), blk, 0, stream>>>(
        ybf, wopb, out, L, DM, DI);
}

// Round 3
// 320.063 us; speedup vs baseline: 2.1638x; 1.2015x over previous
//
#include <hip/hip_runtime.h>
#include <math.h>

// Problem constants (UnifiedMambaBlock, B=1)
#define L      4096
#define DM     768
#define DI     1536
#define DS     16
#define DR     48
#define NCOMB  80     // 48 dt_rank + 16 B + 16 C
#define CH     64     // scan chunk length
#define NC     64     // number of chunks (L / CH)
#define G2_S   16     // GEMM2 K-splits
#define G2_KC  96     // 1536 / 16

typedef unsigned short u16;
typedef unsigned int   u32;
typedef __attribute__((ext_vector_type(8))) short bf16x8;   // 8 bf16 = 4 VGPRs
typedef __attribute__((ext_vector_type(4))) float f32x4;

__device__ __forceinline__ float silu_f(float v) { return v / (1.f + __expf(-v)); }

__device__ __forceinline__ u16 f2bf(float f) {              // RNE f32 -> bf16
    u32 u = __float_as_uint(f);
    return (u16)((u + 0x7fffu + ((u >> 16) & 1u)) >> 16);
}
__device__ __forceinline__ float bf2f(u16 h) {
    return __uint_as_float(((u32)h) << 16);
}

__device__ __forceinline__ void gl_lds16(const u16* g, u16* l) {
    __builtin_amdgcn_global_load_lds(
        (const __attribute__((address_space(1))) void*)g,
        (__attribute__((address_space(3))) void*)l, 16, 0, 0);
}

// ---------------------------------------------------------------------------
// bf16 MFMA GEMM (m97 structure): C[M,N] fp32 = A[M,K] @ W[N,K]^T, bf16 in.
// 128x128 tile, BK=32, 256 threads (4 waves, 2x2 of 64x64), double-buffer LDS.
// ---------------------------------------------------------------------------
__global__ __launch_bounds__(256)
void gemm_bf16_bt(const u16* __restrict__ A, const u16* __restrict__ W,
                  float* __restrict__ C, int M, int N, int K)
{
    __shared__ u16 As[2][128 * 32];
    __shared__ u16 Bs[2][128 * 32];

    const int tid  = threadIdx.x;
    const int lane = tid & 63;
    const int wave = tid >> 6;
    const int wr   = (wave >> 1) * 64;
    const int wc   = (wave & 1) * 64;
    const int m0   = blockIdx.y * 128;
    const int n0   = blockIdx.x * 128;

    const int r0 = tid >> 2;
    const int k0 = (tid & 3) * 8;

    const int frow = lane & 15;
    const int fk   = (lane >> 4) * 8;

    f32x4 acc[4][4];
    #pragma unroll
    for (int i = 0; i < 4; ++i)
        #pragma unroll
        for (int j = 0; j < 4; ++j)
            acc[i][j] = (f32x4){0.f, 0.f, 0.f, 0.f};

    const int NT = K >> 5;

#define STAGE(buf, kk) {                                                       \
        const u16* ga = A + (size_t)(m0 + r0) * K + (kk) + k0;                 \
        const u16* gw = W + (size_t)(n0 + r0) * K + (kk) + k0;                 \
        gl_lds16(ga,                   &As[buf][tid * 8]);                     \
        gl_lds16(ga + (size_t)64 * K,  &As[buf][2048 + tid * 8]);              \
        gl_lds16(gw,                   &Bs[buf][tid * 8]);                     \
        gl_lds16(gw + (size_t)64 * K,  &Bs[buf][2048 + tid * 8]); }

    STAGE(0, 0);
    __syncthreads();

    for (int t = 0; t < NT; ++t) {
        const int b = t & 1;
        if (t + 1 < NT) STAGE(b ^ 1, (t + 1) << 5);

        bf16x8 af[4], bw[4];
        #pragma unroll
        for (int m = 0; m < 4; ++m)
            af[m] = *(const bf16x8*)&As[b][(wr + m * 16 + frow) * 32 + fk];
        #pragma unroll
        for (int n = 0; n < 4; ++n)
            bw[n] = *(const bf16x8*)&Bs[b][(wc + n * 16 + frow) * 32 + fk];

        #pragma unroll
        for (int m = 0; m < 4; ++m)
            #pragma unroll
            for (int n = 0; n < 4; ++n)
                acc[m][n] = __builtin_amdgcn_mfma_f32_16x16x32_bf16(
                    af[m], bw[n], acc[m][n], 0, 0, 0);

        __syncthreads();
    }
#undef STAGE

    const int crow = (lane >> 4) * 4;
    const int ccol = lane & 15;
    #pragma unroll
    for (int m = 0; m < 4; ++m)
        #pragma unroll
        for (int n = 0; n < 4; ++n)
            #pragma unroll
            for (int r = 0; r < 4; ++r)
                C[(size_t)(m0 + wr + m * 16 + crow + r) * N
                  + n0 + wc + n * 16 + ccol] = acc[m][n][r];
}

// ---------------------------------------------------------------------------
// bf16 MFMA GEMM, 128(M)x64(N) tile for narrow-N (GEMM4: N=768 -> 384 blocks)
// 4 waves as 2x2 of 64x32; 8 MFMA / K-step.
// ---------------------------------------------------------------------------
__global__ __launch_bounds__(256)
void gemm_bf16_bt_n64(const u16* __restrict__ A, const u16* __restrict__ W,
                      float* __restrict__ C, int M, int N, int K)
{
    __shared__ u16 As[2][128 * 32];
    __shared__ u16 Bs[2][64 * 32];

    const int tid  = threadIdx.x;
    const int lane = tid & 63;
    const int wave = tid >> 6;
    const int wr   = (wave >> 1) * 64;
    const int wc   = (wave & 1) * 32;
    const int m0   = blockIdx.y * 128;
    const int n0   = blockIdx.x * 64;

    const int r0 = tid >> 2;
    const int k0 = (tid & 3) * 8;

    const int frow = lane & 15;
    const int fk   = (lane >> 4) * 8;

    f32x4 acc[4][2];
    #pragma unroll
    for (int i = 0; i < 4; ++i)
        #pragma unroll
        for (int j = 0; j < 2; ++j)
            acc[i][j] = (f32x4){0.f, 0.f, 0.f, 0.f};

    const int NT = K >> 5;

#define STG(buf, kk) {                                                         \
        const u16* ga = A + (size_t)(m0 + r0) * K + (kk) + k0;                 \
        gl_lds16(ga,                   &As[buf][tid * 8]);                     \
        gl_lds16(ga + (size_t)64 * K,  &As[buf][2048 + tid * 8]);              \
        gl_lds16(W + (size_t)(n0 + r0) * K + (kk) + k0, &Bs[buf][tid * 8]); }

    STG(0, 0);
    __syncthreads();

    for (int t = 0; t < NT; ++t) {
        const int b = t & 1;
        if (t + 1 < NT) STG(b ^ 1, (t + 1) << 5);

        bf16x8 af[4], bw[2];
        #pragma unroll
        for (int m = 0; m < 4; ++m)
            af[m] = *(const bf16x8*)&As[b][(wr + m * 16 + frow) * 32 + fk];
        #pragma unroll
        for (int n = 0; n < 2; ++n)
            bw[n] = *(const bf16x8*)&Bs[b][(wc + n * 16 + frow) * 32 + fk];

        #pragma unroll
        for (int m = 0; m < 4; ++m)
            #pragma unroll
            for (int n = 0; n < 2; ++n)
                acc[m][n] = __builtin_amdgcn_mfma_f32_16x16x32_bf16(
                    af[m], bw[n], acc[m][n], 0, 0, 0);

        __syncthreads();
    }
#undef STG

    const int crow = (lane >> 4) * 4;
    const int ccol = lane & 15;
    #pragma unroll
    for (int m = 0; m < 4; ++m)
        #pragma unroll
        for (int n = 0; n < 2; ++n)
            #pragma unroll
            for (int r = 0; r < 4; ++r)
                C[(size_t)(m0 + wr + m * 16 + crow + r) * N
                  + n0 + wc + n * 16 + ccol] = acc[m][n][r];
}

// ---------------------------------------------------------------------------
// split-3 packs for fp32-grade bf16 MFMA:  A:[hi|lo|hi]  W:[hi|hi|lo]
// ---------------------------------------------------------------------------
__global__ __launch_bounds__(256)
void pack_split3_k(const float* __restrict__ in, u16* __restrict__ out,
                   int MK4, int K)
{
    int i = blockIdx.x * 256 + threadIdx.x;
    if (i >= MK4) return;
    const float4 v = ((const float4*)in)[i];
    const int e = i * 4;
    const int r = e / K, c = e - r * K;
    const float f[4] = {v.x, v.y, v.z, v.w};
    ushort4 hi, lo;
    u16 h, l;
    h = f2bf(f[0]); l = f2bf(f[0] - bf2f(h)); hi.x = h; lo.x = l;
    h = f2bf(f[1]); l = f2bf(f[1] - bf2f(h)); hi.y = h; lo.y = l;
    h = f2bf(f[2]); l = f2bf(f[2] - bf2f(h)); hi.z = h; lo.z = l;
    h = f2bf(f[3]); l = f2bf(f[3] - bf2f(h)); hi.w = h; lo.w = l;
    u16* row = out + (size_t)r * 3 * K + c;
    *(ushort4*)(row)         = hi;
    *(ushort4*)(row + K)     = lo;
    *(ushort4*)(row + 2 * K) = hi;
}

__global__ __launch_bounds__(256)
void pack_split3w_k(const float* __restrict__ in, u16* __restrict__ out,
                    int MK4, int K)
{
    int i = blockIdx.x * 256 + threadIdx.x;
    if (i >= MK4) return;
    const float4 v = ((const float4*)in)[i];
    const int e = i * 4;
    const int r = e / K, c = e - r * K;
    const float f[4] = {v.x, v.y, v.z, v.w};
    ushort4 hi, lo;
    u16 h, l;
    h = f2bf(f[0]); l = f2bf(f[0] - bf2f(h)); hi.x = h; lo.x = l;
    h = f2bf(f[1]); l = f2bf(f[1] - bf2f(h)); hi.y = h; lo.y = l;
    h = f2bf(f[2]); l = f2bf(f[2] - bf2f(h)); hi.z = h; lo.z = l;
    h = f2bf(f[3]); l = f2bf(f[3] - bf2f(h)); hi.w = h; lo.w = l;
    u16* row = out + (size_t)r * 3 * K + c;
    *(ushort4*)(row)         = hi;
    *(ushort4*)(row + K)     = hi;
    *(ushort4*)(row + 2 * K) = lo;
}

__global__ __launch_bounds__(256)
void pack_bf16_k(const float* __restrict__ in, u16* __restrict__ out, int N4)
{
    int i = blockIdx.x * 256 + threadIdx.x;
    if (i >= N4) return;
    const float4 v = ((const float4*)in)[i];
    ushort4 o;
    o.x = f2bf(v.x); o.y = f2bf(v.y); o.z = f2bf(v.z); o.w = f2bf(v.w);
    ((ushort4*)out)[i] = o;
}

// ---------------------------------------------------------------------------
// Generic fp32 GEMM (kept for GEMM3). EPI 1: softplus(acc + bias[col])
// ---------------------------------------------------------------------------
template <int EPI>
__global__ __launch_bounds__(256)
void gemm_f32(const float* __restrict__ A, int lda,
              const float* __restrict__ W,
              const float* __restrict__ bias,
              float* __restrict__ C,
              int M, int N, int K)
{
    __shared__ float As[16][64];
    __shared__ float Ws[16][64];

    const int tid = threadIdx.x;
    const int tx = tid & 15;
    const int ty = tid >> 4;
    const int m0 = blockIdx.y * 64;
    const int n0 = blockIdx.x * 64;

    const int lrow = tid >> 2;
    const int lk   = (tid & 3) * 4;

    float acc[4][4] = {{0.f}};

    for (int kk = 0; kk < K; kk += 16) {
        {
            const float4 v = *(const float4*)(A + (size_t)(m0 + lrow) * lda + kk + lk);
            As[lk + 0][lrow] = v.x; As[lk + 1][lrow] = v.y;
            As[lk + 2][lrow] = v.z; As[lk + 3][lrow] = v.w;
        }
        {
            float4 v = make_float4(0.f, 0.f, 0.f, 0.f);
            if (n0 + lrow < N)
                v = *(const float4*)(W + (size_t)(n0 + lrow) * K + kk + lk);
            Ws[lk + 0][lrow] = v.x; Ws[lk + 1][lrow] = v.y;
            Ws[lk + 2][lrow] = v.z; Ws[lk + 3][lrow] = v.w;
        }
        __syncthreads();

        #pragma unroll
        for (int k = 0; k < 16; ++k) {
            const float4 av = *(const float4*)&As[k][ty * 4];
            const float4 bv = *(const float4*)&Ws[k][tx * 4];
            const float a[4] = {av.x, av.y, av.z, av.w};
            const float b[4] = {bv.x, bv.y, bv.z, bv.w};
            #pragma unroll
            for (int i = 0; i < 4; ++i)
                #pragma unroll
                for (int j = 0; j < 4; ++j)
                    acc[i][j] = fmaf(a[i], b[j], acc[i][j]);
        }
        __syncthreads();
    }

    const int col = n0 + tx * 4;
    if (col < N) {
        #pragma unroll
        for (int i = 0; i < 4; ++i) {
            const int row = m0 + ty * 4 + i;
            float4 v;
            float r[4];
            #pragma unroll
            for (int j = 0; j < 4; ++j) {
                float x = acc[i][j];
                if (EPI == 1) {
                    x += bias[col + j];
                    x = (x > 20.f) ? x : log1pf(expf(x));
                }
                r[j] = x;
            }
            v.x = r[0]; v.y = r[1]; v.z = r[2]; v.w = r[3];
            *(float4*)(C + (size_t)row * N + col) = v;
        }
    }
}

// ---------------------------------------------------------------------------
// GEMM2 split-K: dtbc[L][80] = xcv[L][DI] @ Wt[DI][80]
// grid (64 M-tiles, 16 K-splits); whole chunk staged once, no inner barrier.
// ---------------------------------------------------------------------------
__global__ __launch_bounds__(256)
void gemm2_splitk(const float* __restrict__ A, const float* __restrict__ Wt,
                  float* __restrict__ part)
{
    __shared__ float As[G2_KC][64];
    __shared__ float Ws[G2_KC][80];

    const int tid  = threadIdx.x;
    const int m0   = blockIdx.x * 64;
    const int koff = blockIdx.y * G2_KC;

    // stage A: 64 rows x 96 k, k-major in LDS
    {
        const int r = tid >> 2, cg = tid & 3;
        #pragma unroll
        for (int j = 0; j < 6; ++j) {
            const int kk = (j * 4 + cg) * 4;
            const float4 v = *(const float4*)(A + (size_t)(m0 + r) * DI + koff + kk);
            As[kk + 0][r] = v.x; As[kk + 1][r] = v.y;
            As[kk + 2][r] = v.z; As[kk + 3][r] = v.w;
        }
    }
    // stage W: 96 k x 80 n (Wt is k-major, coalesced)
    for (int i = tid; i < G2_KC * 80; i += 256)
        (&Ws[0][0])[i] = Wt[(size_t)koff * 80 + i];
    __syncthreads();

    const int g  = tid >> 6;    // wave -> 20-col strip
    const int r  = tid & 63;    // lane -> row
    const int c0 = g * 20;

    float acc[20];
    #pragma unroll
    for (int j = 0; j < 20; ++j) acc[j] = 0.f;

    #pragma unroll 2
    for (int k = 0; k < G2_KC; ++k) {
        const float a = As[k][r];
        #pragma unroll
        for (int q = 0; q < 5; ++q) {
            const float4 w = *(const float4*)&Ws[k][c0 + q * 4];
            acc[q * 4 + 0] = fmaf(a, w.x, acc[q * 4 + 0]);
            acc[q * 4 + 1] = fmaf(a, w.y, acc[q * 4 + 1]);
            acc[q * 4 + 2] = fmaf(a, w.z, acc[q * 4 + 2]);
            acc[q * 4 + 3] = fmaf(a, w.w, acc[q * 4 + 3]);
        }
    }

    float* p = part + (size_t)blockIdx.y * (L * NCOMB)
                    + (size_t)(m0 + r) * NCOMB + c0;
    #pragma unroll
    for (int q = 0; q < 5; ++q)
        ((float4*)p)[q] = make_float4(acc[q * 4], acc[q * 4 + 1],
                                      acc[q * 4 + 2], acc[q * 4 + 3]);
}

__global__ __launch_bounds__(256)
void gemm2_reduce(const float* __restrict__ part, float* __restrict__ dtbc)
{
    int i = blockIdx.x * 256 + threadIdx.x;
    if (i >= L * NCOMB) return;
    float s = 0.f;
    #pragma unroll
    for (int j = 0; j < G2_S; ++j)
        s += part[(size_t)j * L * NCOMB + i];
    dtbc[i] = s;
}

// ---------------------------------------------------------------------------
// pack transposed combined projection weights: Wt[1536][80]
// ---------------------------------------------------------------------------
__global__ void pack_wct_k(const float* __restrict__ xdt, const float* __restrict__ xb,
                           const float* __restrict__ xc, float* __restrict__ Wt)
{
    int i = blockIdx.x * 256 + threadIdx.x;
    if (i >= DI * NCOMB) return;
    int k = i / NCOMB, n = i - k * NCOMB;
    float v;
    if (n < 48)      v = xdt[n * DI + k];
    else if (n < 64) v = xb[(n - 48) * DI + k];
    else             v = xc[(n - 64) * DI + k];
    Wt[i] = v;
}

// ---------------------------------------------------------------------------
__global__ __launch_bounds__(256)
void conv_silu_k(const float* __restrict__ xz, const float* __restrict__ cw,
                 const float* __restrict__ cb, float* __restrict__ xcv)
{
    int idx = blockIdx.x * 256 + threadIdx.x;
    if (idx >= L * DI) return;
    int t = idx / DI, d = idx - t * DI;
    const float4 w = *(const float4*)(cw + d * 4);
    const float* xcol = xz + d;
    float acc = cb[d];
    if (t >= 3) acc = fmaf(w.x, xcol[(size_t)(t - 3) * (2 * DI)], acc);
    if (t >= 2) acc = fmaf(w.y, xcol[(size_t)(t - 2) * (2 * DI)], acc);
    if (t >= 1) acc = fmaf(w.z, xcol[(size_t)(t - 1) * (2 * DI)], acc);
    acc = fmaf(w.w, xcol[(size_t)t * (2 * DI)], acc);
    xcv[idx] = silu_f(acc);
}

__global__ __launch_bounds__(256)
void scan1_k(const float* __restrict__ dt, const float* __restrict__ xcv,
             const float* __restrict__ dtbc, const float* __restrict__ alog,
             float* __restrict__ hloc, float* __restrict__ Ssum)
{
    __shared__ float Bs[CH][DS];
    const int c = blockIdx.y;
    const int d = blockIdx.x * 256 + threadIdx.x;

    for (int i = threadIdx.x; i < CH * DS; i += 256) {
        int tt = i >> 4, n = i & 15;
        Bs[tt][n] = dtbc[(size_t)(c * CH + tt) * NCOMB + 48 + n];
    }
    __syncthreads();

    float Ad[DS], h[DS];
    #pragma unroll
    for (int n = 0; n < DS; ++n) {
        Ad[n] = -expf(alog[d * DS + n]);
        h[n] = 0.f;
    }

    size_t base = (size_t)(c * CH) * DI + d;
    float S = 0.f;
    for (int tt = 0; tt < CH; ++tt, base += DI) {
        const float dtv = dt[base];
        const float xv  = xcv[base];
        S += dtv;
        const float xdt = xv * dtv;
        #pragma unroll
        for (int n = 0; n < DS; ++n)
            h[n] = fmaf(h[n], __expf(Ad[n] * dtv), xdt * Bs[tt][n]);
    }

    const size_t o = ((size_t)c * DI + d) * DS;
    #pragma unroll
    for (int n = 0; n < DS; ++n) hloc[o + n] = h[n];
    Ssum[c * DI + d] = S;
}

__global__ __launch_bounds__(256)
void scan2_k(float* hc, const float* __restrict__ Ssum,
             const float* __restrict__ alog)
{
    const int p = blockIdx.x * 256 + threadIdx.x;
    if (p >= DI * DS) return;
    const int d = p >> 4;
    const float Ad = -expf(alog[p]);
    float h = 0.f;
    for (int c = 0; c < NC; ++c) {
        const size_t o = (size_t)c * DI * DS + p;
        const float hl = hc[o];
        hc[o] = h;
        h = fmaf(h, __expf(Ad * Ssum[c * DI + d]), hl);
    }
}

__global__ __launch_bounds__(256)
void scan3_k(float* dty, const float* __restrict__ xcv,
             const float* __restrict__ dtbc, const float* __restrict__ alog,
             const float* __restrict__ carry, const float* __restrict__ Dp,
             const float* __restrict__ xz)
{
    __shared__ float Bs[CH][DS];
    __shared__ float Cs[CH][DS];
    const int c = blockIdx.y;
    const int d = blockIdx.x * 256 + threadIdx.x;

    for (int i = threadIdx.x; i < CH * DS; i += 256) {
        int tt = i >> 4, n = i & 15;
        Bs[tt][n] = dtbc[(size_t)(c * CH + tt) * NCOMB + 48 + n];
        Cs[tt][n] = dtbc[(size_t)(c * CH + tt) * NCOMB + 64 + n];
    }
    __syncthreads();

    float Ad[DS], h[DS];
    const size_t co = ((size_t)c * DI + d) * DS;
    #pragma unroll
    for (int n = 0; n < DS; ++n) {
        Ad[n] = -expf(alog[d * DS + n]);
        h[n] = carry[co + n];
    }
    const float Dv = Dp[d];

    int t = c * CH;
    for (int tt = 0; tt < CH; ++tt, ++t) {
        const size_t o = (size_t)t * DI + d;
        const float dtv = dty[o];
        const float xv  = xcv[o];
        const float xdt = xv * dtv;
        float y = Dv * xv;
        #pragma unroll
        for (int n = 0; n < DS; ++n) {
            h[n] = fmaf(h[n], __expf(Ad[n] * dtv), xdt * Bs[tt][n]);
            y = fmaf(h[n], Cs[tt][n], y);
        }
        const float z = xz[(size_t)t * (2 * DI) + DI + d];
        dty[o] = y * silu_f(z);
    }
}

// ---------------------------------------------------------------------------
extern "C" void kernel_launch(void* const* d_in, const int* in_sizes, int n_in,
                              void* d_out, int out_size, void* d_ws, size_t ws_size,
                              hipStream_t stream)
{
    const float* u    = (const float*)d_in[0];
    const float* Wip  = (const float*)d_in[1];
    const float* cw   = (const float*)d_in[2];
    const float* cb   = (const float*)d_in[3];
    const float* xdt  = (const float*)d_in[4];
    const float* xbw  = (const float*)d_in[5];
    const float* xcw  = (const float*)d_in[6];
    const float* dtw  = (const float*)d_in[7];
    const float* dtb  = (const float*)d_in[8];
    const float* alog = (const float*)d_in[9];
    const float* Dp   = (const float*)d_in[10];
    const float* Wop  = (const float*)d_in[11];
    float* out = (float*)d_out;

    // workspace layout (floats) — same 109 MB footprint
    float* ws   = (float*)d_ws;
    float* xz   = ws;                                // L*2*DI
    float* xcv  = xz   + (size_t)L * 2 * DI;         // L*DI
    float* dtbc = xcv  + (size_t)L * DI;             // L*NCOMB
    float* dty  = dtbc + (size_t)L * NCOMB;          // L*DI
    float* Wt   = dty  + (size_t)L * DI;             // DI*NCOMB
    float* hc   = Wt   + (size_t)DI * NCOMB;         // NC*DI*DS
    float* Ssum = hc   + (size_t)NC * DI * DS;       // NC*DI

    // aliases into regions dead at time of use
    u16*   u3   = (u16*)xcv;                 // [4096][2304] bf16 (dead after GEMM1)
    u16*   W3   = (u16*)dty;                 // [3072][2304] bf16 (dead after GEMM1)
    float* g2p  = dty;                       // [16][4096][80] fp32 = 5.24M floats (< L*DI)
    u16*   ybf  = (u16*)xz;                  // [4096][1536] bf16 (xz dead after scan3)
    u16*   wopb = (u16*)xz + (size_t)L * DI; // [768][1536] bf16

    const dim3 blk(256);

    // 1) split-3 packs for GEMM1
    pack_split3_k<<<(L * DM / 4 + 255) / 256, blk, 0, stream>>>(u, u3, L * DM / 4, DM);
    pack_split3w_k<<<(2 * DI * DM / 4 + 255) / 256, blk, 0, stream>>>(Wip, W3, 2 * DI * DM / 4, DM);

    // 2) xz = u @ in_proj_w^T   [4096, 3072]  (bf16 MFMA, K'=3*768)
    gemm_bf16_bt<<<dim3((2 * DI) / 128, L / 128), blk, 0, stream>>>(
        u3, W3, xz, L, 2 * DI, 3 * DM);

    // 3) transposed combined projection weights  Wt[1536][80]
    pack_wct_k<<<(DI * NCOMB + 255) / 256, blk, 0, stream>>>(xdt, xbw, xcw, Wt);

    // 4) causal depthwise conv + SiLU -> x_conv  (overwrites u3 region)
    conv_silu_k<<<(L * DI + 255) / 256, blk, 0, stream>>>(xz, cw, cb, xcv);

    // 5) [dt_rank | B | C] = x_conv @ Wt  via split-K (partials in dead dty region)
    gemm2_splitk<<<dim3(L / 64, G2_S), blk, 0, stream>>>(xcv, Wt, g2p);
    gemm2_reduce<<<(L * NCOMB + 255) / 256, blk, 0, stream>>>(g2p, dtbc);

    // 6) dt = softplus(dt_rank @ dt_w^T + dt_b)  [4096, 1536] (overwrites partials)
    gemm_f32<1><<<dim3(DI / 64, L / 64), blk, 0, stream>>>(
        dtbc, NCOMB, dtw, dtb, dty, L, DI, DR);

    // 7-9) chunked selective scan -> yz (in dty)
    scan1_k<<<dim3(DI / 256, NC), blk, 0, stream>>>(dty, xcv, dtbc, alog, hc, Ssum);
    scan2_k<<<(DI * DS) / 256, blk, 0, stream>>>(hc, Ssum, alog);
    scan3_k<<<dim3(DI / 256, NC), blk, 0, stream>>>(dty, xcv, dtbc, alog, hc, Dp, xz);

    // 10) bf16 packs for GEMM4 (xz region dead now)
    pack_bf16_k<<<(L * DI / 4 + 255) / 256, blk, 0, stream>>>(dty, ybf, L * DI / 4);
    pack_bf16_k<<<(DM * DI / 4 + 255) / 256, blk, 0, stream>>>(Wop, wopb, DM * DI / 4);

    // 11) out = yz @ out_proj_w^T   [4096, 768]  (bf16 MFMA, 128x64 tile)
    gemm_bf16_bt_n64<<<dim3(DM / 64, L / 128), blk, 0, stream>>>(
        ybf, wopb, out, L, DM, DI);
}

// Round 4
// 299.788 us; speedup vs baseline: 2.3102x; 1.0676x over previous
//
#include <hip/hip_runtime.h>
#include <math.h>

// Problem constants (UnifiedMambaBlock, B=1)
#define L      4096
#define DM     768
#define DI     1536
#define DS     16
#define DR     48
#define NCOMB  80     // 48 dt_rank + 16 B + 16 C
#define CH     64     // scan chunk length
#define NC     64     // number of chunks (L / CH)
#define G2_S   16     // GEMM2 K-splits
#define G2_KC  96     // 1536 / 16

typedef unsigned short u16;
typedef unsigned int   u32;
typedef __attribute__((ext_vector_type(8))) short bf16x8;   // 8 bf16 = 4 VGPRs
typedef __attribute__((ext_vector_type(4))) float f32x4;

__device__ __forceinline__ float silu_f(float v) { return v / (1.f + __expf(-v)); }

__device__ __forceinline__ u16 f2bf(float f) {              // RNE f32 -> bf16
    u32 u = __float_as_uint(f);
    return (u16)((u + 0x7fffu + ((u >> 16) & 1u)) >> 16);
}

__device__ __forceinline__ void gl_lds16(const u16* g, u16* l) {
    __builtin_amdgcn_global_load_lds(
        (const __attribute__((address_space(1))) void*)g,
        (__attribute__((address_space(3))) void*)l, 16, 0, 0);
}

// ---------------------------------------------------------------------------
// bf16 MFMA GEMM (m97 structure): C[M,N] fp32 = A[M,K] @ W[N,K]^T, bf16 in.
// 128x128 tile, BK=32, 256 threads (4 waves, 2x2 of 64x64), double-buffer LDS.
// ---------------------------------------------------------------------------
__global__ __launch_bounds__(256)
void gemm_bf16_bt(const u16* __restrict__ A, const u16* __restrict__ W,
                  float* __restrict__ C, int M, int N, int K)
{
    __shared__ u16 As[2][128 * 32];
    __shared__ u16 Bs[2][128 * 32];

    const int tid  = threadIdx.x;
    const int lane = tid & 63;
    const int wave = tid >> 6;
    const int wr   = (wave >> 1) * 64;
    const int wc   = (wave & 1) * 64;
    const int m0   = blockIdx.y * 128;
    const int n0   = blockIdx.x * 128;

    const int r0 = tid >> 2;
    const int k0 = (tid & 3) * 8;

    const int frow = lane & 15;
    const int fk   = (lane >> 4) * 8;

    f32x4 acc[4][4];
    #pragma unroll
    for (int i = 0; i < 4; ++i)
        #pragma unroll
        for (int j = 0; j < 4; ++j)
            acc[i][j] = (f32x4){0.f, 0.f, 0.f, 0.f};

    const int NT = K >> 5;

#define STAGE(buf, kk) {                                                       \
        const u16* ga = A + (size_t)(m0 + r0) * K + (kk) + k0;                 \
        const u16* gw = W + (size_t)(n0 + r0) * K + (kk) + k0;                 \
        gl_lds16(ga,                   &As[buf][tid * 8]);                     \
        gl_lds16(ga + (size_t)64 * K,  &As[buf][2048 + tid * 8]);              \
        gl_lds16(gw,                   &Bs[buf][tid * 8]);                     \
        gl_lds16(gw + (size_t)64 * K,  &Bs[buf][2048 + tid * 8]); }

    STAGE(0, 0);
    __syncthreads();

    for (int t = 0; t < NT; ++t) {
        const int b = t & 1;
        if (t + 1 < NT) STAGE(b ^ 1, (t + 1) << 5);

        bf16x8 af[4], bw[4];
        #pragma unroll
        for (int m = 0; m < 4; ++m)
            af[m] = *(const bf16x8*)&As[b][(wr + m * 16 + frow) * 32 + fk];
        #pragma unroll
        for (int n = 0; n < 4; ++n)
            bw[n] = *(const bf16x8*)&Bs[b][(wc + n * 16 + frow) * 32 + fk];

        #pragma unroll
        for (int m = 0; m < 4; ++m)
            #pragma unroll
            for (int n = 0; n < 4; ++n)
                acc[m][n] = __builtin_amdgcn_mfma_f32_16x16x32_bf16(
                    af[m], bw[n], acc[m][n], 0, 0, 0);

        __syncthreads();
    }
#undef STAGE

    const int crow = (lane >> 4) * 4;
    const int ccol = lane & 15;
    #pragma unroll
    for (int m = 0; m < 4; ++m)
        #pragma unroll
        for (int n = 0; n < 4; ++n)
            #pragma unroll
            for (int r = 0; r < 4; ++r)
                C[(size_t)(m0 + wr + m * 16 + crow + r) * N
                  + n0 + wc + n * 16 + ccol] = acc[m][n][r];
}

// ---------------------------------------------------------------------------
// bf16 MFMA GEMM, 128(M)x64(N) tile for narrow-N (GEMM4: N=768 -> 384 blocks)
// ---------------------------------------------------------------------------
__global__ __launch_bounds__(256)
void gemm_bf16_bt_n64(const u16* __restrict__ A, const u16* __restrict__ W,
                      float* __restrict__ C, int M, int N, int K)
{
    __shared__ u16 As[2][128 * 32];
    __shared__ u16 Bs[2][64 * 32];

    const int tid  = threadIdx.x;
    const int lane = tid & 63;
    const int wave = tid >> 6;
    const int wr   = (wave >> 1) * 64;
    const int wc   = (wave & 1) * 32;
    const int m0   = blockIdx.y * 128;
    const int n0   = blockIdx.x * 64;

    const int r0 = tid >> 2;
    const int k0 = (tid & 3) * 8;

    const int frow = lane & 15;
    const int fk   = (lane >> 4) * 8;

    f32x4 acc[4][2];
    #pragma unroll
    for (int i = 0; i < 4; ++i)
        #pragma unroll
        for (int j = 0; j < 2; ++j)
            acc[i][j] = (f32x4){0.f, 0.f, 0.f, 0.f};

    const int NT = K >> 5;

#define STG(buf, kk) {                                                         \
        const u16* ga = A + (size_t)(m0 + r0) * K + (kk) + k0;                 \
        gl_lds16(ga,                   &As[buf][tid * 8]);                     \
        gl_lds16(ga + (size_t)64 * K,  &As[buf][2048 + tid * 8]);              \
        gl_lds16(W + (size_t)(n0 + r0) * K + (kk) + k0, &Bs[buf][tid * 8]); }

    STG(0, 0);
    __syncthreads();

    for (int t = 0; t < NT; ++t) {
        const int b = t & 1;
        if (t + 1 < NT) STG(b ^ 1, (t + 1) << 5);

        bf16x8 af[4], bw[2];
        #pragma unroll
        for (int m = 0; m < 4; ++m)
            af[m] = *(const bf16x8*)&As[b][(wr + m * 16 + frow) * 32 + fk];
        #pragma unroll
        for (int n = 0; n < 2; ++n)
            bw[n] = *(const bf16x8*)&Bs[b][(wc + n * 16 + frow) * 32 + fk];

        #pragma unroll
        for (int m = 0; m < 4; ++m)
            #pragma unroll
            for (int n = 0; n < 2; ++n)
                acc[m][n] = __builtin_amdgcn_mfma_f32_16x16x32_bf16(
                    af[m], bw[n], acc[m][n], 0, 0, 0);

        __syncthreads();
    }
#undef STG

    const int crow = (lane >> 4) * 4;
    const int ccol = lane & 15;
    #pragma unroll
    for (int m = 0; m < 4; ++m)
        #pragma unroll
        for (int n = 0; n < 2; ++n)
            #pragma unroll
            for (int r = 0; r < 4; ++r)
                C[(size_t)(m0 + wr + m * 16 + crow + r) * N
                  + n0 + wc + n * 16 + ccol] = acc[m][n][r];
}

// ---------------------------------------------------------------------------
// Early pack: u -> ubf (bf16), Wip -> Wipb (bf16), [xdt;xb;xc]^T -> Wt (fp32)
// ---------------------------------------------------------------------------
#define NU4  (L * DM / 4)            // 786432
#define NW4  (2 * DI * DM / 4)       // 589824
#define NWT  (DI * NCOMB)            // 122880
__global__ __launch_bounds__(256)
void pack_early_k(const float* __restrict__ u, const float* __restrict__ Wip,
                  const float* __restrict__ xdt, const float* __restrict__ xb,
                  const float* __restrict__ xc,
                  u16* __restrict__ ubf, u16* __restrict__ Wipb,
                  float* __restrict__ Wt)
{
    int i = blockIdx.x * 256 + threadIdx.x;
    if (i < NU4) {
        const float4 v = ((const float4*)u)[i];
        ushort4 o; o.x = f2bf(v.x); o.y = f2bf(v.y); o.z = f2bf(v.z); o.w = f2bf(v.w);
        ((ushort4*)ubf)[i] = o;
        return;
    }
    i -= NU4;
    if (i < NW4) {
        const float4 v = ((const float4*)Wip)[i];
        ushort4 o; o.x = f2bf(v.x); o.y = f2bf(v.y); o.z = f2bf(v.z); o.w = f2bf(v.w);
        ((ushort4*)Wipb)[i] = o;
        return;
    }
    i -= NW4;
    if (i < NWT) {
        const int k = i / NCOMB, n = i - k * NCOMB;
        float v;
        if (n < 48)      v = xdt[n * DI + k];
        else if (n < 64) v = xb[(n - 48) * DI + k];
        else             v = xc[(n - 64) * DI + k];
        Wt[i] = v;
    }
}

// Late pack: yz(fp32) -> ybf, Wop -> wopb
#define NY4  (L * DI / 4)            // 1572864
#define NO4  (DM * DI / 4)           // 294912
__global__ __launch_bounds__(256)
void pack_late_k(const float* __restrict__ yz, const float* __restrict__ Wop,
                 u16* __restrict__ ybf, u16* __restrict__ wopb)
{
    int i = blockIdx.x * 256 + threadIdx.x;
    if (i < NY4) {
        const float4 v = ((const float4*)yz)[i];
        ushort4 o; o.x = f2bf(v.x); o.y = f2bf(v.y); o.z = f2bf(v.z); o.w = f2bf(v.w);
        ((ushort4*)ybf)[i] = o;
        return;
    }
    i -= NY4;
    if (i < NO4) {
        const float4 v = ((const float4*)Wop)[i];
        ushort4 o; o.x = f2bf(v.x); o.y = f2bf(v.y); o.z = f2bf(v.z); o.w = f2bf(v.w);
        ((ushort4*)wopb)[i] = o;
    }
}

// ---------------------------------------------------------------------------
// Generic fp32 GEMM (kept for GEMM3). EPI 1: softplus(acc + bias[col])
// ---------------------------------------------------------------------------
template <int EPI>
__global__ __launch_bounds__(256)
void gemm_f32(const float* __restrict__ A, int lda,
              const float* __restrict__ W,
              const float* __restrict__ bias,
              float* __restrict__ C,
              int M, int N, int K)
{
    __shared__ float As[16][64];
    __shared__ float Ws[16][64];

    const int tid = threadIdx.x;
    const int tx = tid & 15;
    const int ty = tid >> 4;
    const int m0 = blockIdx.y * 64;
    const int n0 = blockIdx.x * 64;

    const int lrow = tid >> 2;
    const int lk   = (tid & 3) * 4;

    float acc[4][4] = {{0.f}};

    for (int kk = 0; kk < K; kk += 16) {
        {
            const float4 v = *(const float4*)(A + (size_t)(m0 + lrow) * lda + kk + lk);
            As[lk + 0][lrow] = v.x; As[lk + 1][lrow] = v.y;
            As[lk + 2][lrow] = v.z; As[lk + 3][lrow] = v.w;
        }
        {
            float4 v = make_float4(0.f, 0.f, 0.f, 0.f);
            if (n0 + lrow < N)
                v = *(const float4*)(W + (size_t)(n0 + lrow) * K + kk + lk);
            Ws[lk + 0][lrow] = v.x; Ws[lk + 1][lrow] = v.y;
            Ws[lk + 2][lrow] = v.z; Ws[lk + 3][lrow] = v.w;
        }
        __syncthreads();

        #pragma unroll
        for (int k = 0; k < 16; ++k) {
            const float4 av = *(const float4*)&As[k][ty * 4];
            const float4 bv = *(const float4*)&Ws[k][tx * 4];
            const float a[4] = {av.x, av.y, av.z, av.w};
            const float b[4] = {bv.x, bv.y, bv.z, bv.w};
            #pragma unroll
            for (int i = 0; i < 4; ++i)
                #pragma unroll
                for (int j = 0; j < 4; ++j)
                    acc[i][j] = fmaf(a[i], b[j], acc[i][j]);
        }
        __syncthreads();
    }

    const int col = n0 + tx * 4;
    if (col < N) {
        #pragma unroll
        for (int i = 0; i < 4; ++i) {
            const int row = m0 + ty * 4 + i;
            float4 v;
            float r[4];
            #pragma unroll
            for (int j = 0; j < 4; ++j) {
                float x = acc[i][j];
                if (EPI == 1) {
                    x += bias[col + j];
                    x = (x > 20.f) ? x : log1pf(expf(x));
                }
                r[j] = x;
            }
            v.x = r[0]; v.y = r[1]; v.z = r[2]; v.w = r[3];
            *(float4*)(C + (size_t)row * N + col) = v;
        }
    }
}

// ---------------------------------------------------------------------------
// GEMM2 split-K with FUSED causal conv + SiLU:
//   x_conv tile (64 t x 96 ch) computed from xz, written to xcv AND kept in
//   LDS as As[96][65]; then partial dtbc = As^T @ Ws.
// grid (64 M-tiles, 16 ch-splits) covers xcv exactly once.
// ---------------------------------------------------------------------------
__global__ __launch_bounds__(256)
void gemm2_conv_splitk(const float* __restrict__ xz, const float* __restrict__ cw,
                       const float* __restrict__ cb, const float* __restrict__ Wt,
                       float* __restrict__ xcv, float* __restrict__ part)
{
    __shared__ float As[G2_KC][65];     // +1 pad: conflict-free col-major write
    __shared__ float Ws[G2_KC][80];
    __shared__ float cw_s[G2_KC * 4];
    __shared__ float cb_s[G2_KC];

    const int tid  = threadIdx.x;
    const int m0   = blockIdx.x * 64;
    const int koff = blockIdx.y * G2_KC;   // channel offset

    // stage conv weights + combined projection weights
    for (int i = tid; i < G2_KC * 4; i += 256) cw_s[i] = cw[(size_t)koff * 4 + i];
    if (tid < G2_KC) cb_s[tid] = cb[koff + tid];
    for (int i = tid; i < G2_KC * 80; i += 256)
        (&Ws[0][0])[i] = Wt[(size_t)koff * 80 + i];
    __syncthreads();

    // conv + silu for rows m0..m0+63, channels koff..koff+95
    for (int i = tid; i < 64 * G2_KC; i += 256) {
        const int r = i / G2_KC, c = i - r * G2_KC;
        float acc = cb_s[c];
        #pragma unroll
        for (int j = 0; j < 4; ++j) {
            const int t = m0 + r - 3 + j;
            if (t >= 0)
                acc = fmaf(cw_s[c * 4 + j], xz[(size_t)t * (2 * DI) + koff + c], acc);
        }
        const float v = silu_f(acc);
        As[c][r] = v;
        xcv[(size_t)(m0 + r) * DI + koff + c] = v;
    }
    __syncthreads();

    const int g  = tid >> 6;    // wave -> 20-col strip
    const int r  = tid & 63;    // lane -> row
    const int c0 = g * 20;

    float acc[20];
    #pragma unroll
    for (int j = 0; j < 20; ++j) acc[j] = 0.f;

    #pragma unroll 2
    for (int k = 0; k < G2_KC; ++k) {
        const float a = As[k][r];
        #pragma unroll
        for (int q = 0; q < 5; ++q) {
            const float4 w = *(const float4*)&Ws[k][c0 + q * 4];
            acc[q * 4 + 0] = fmaf(a, w.x, acc[q * 4 + 0]);
            acc[q * 4 + 1] = fmaf(a, w.y, acc[q * 4 + 1]);
            acc[q * 4 + 2] = fmaf(a, w.z, acc[q * 4 + 2]);
            acc[q * 4 + 3] = fmaf(a, w.w, acc[q * 4 + 3]);
        }
    }

    float* p = part + (size_t)blockIdx.y * (L * NCOMB)
                    + (size_t)(m0 + r) * NCOMB + c0;
    #pragma unroll
    for (int q = 0; q < 5; ++q)
        ((float4*)p)[q] = make_float4(acc[q * 4], acc[q * 4 + 1],
                                      acc[q * 4 + 2], acc[q * 4 + 3]);
}

__global__ __launch_bounds__(256)
void gemm2_reduce(const float* __restrict__ part, float* __restrict__ dtbc)
{
    int i = blockIdx.x * 256 + threadIdx.x;
    if (i >= L * NCOMB) return;
    float s = 0.f;
    #pragma unroll
    for (int j = 0; j < G2_S; ++j)
        s += part[(size_t)j * L * NCOMB + i];
    dtbc[i] = s;
}

// ---------------------------------------------------------------------------
__global__ __launch_bounds__(256)
void scan1_k(const float* __restrict__ dt, const float* __restrict__ xcv,
             const float* __restrict__ dtbc, const float* __restrict__ alog,
             float* __restrict__ hloc, float* __restrict__ Ssum)
{
    __shared__ float Bs[CH][DS];
    const int c = blockIdx.y;
    const int d = blockIdx.x * 256 + threadIdx.x;

    for (int i = threadIdx.x; i < CH * DS; i += 256) {
        int tt = i >> 4, n = i & 15;
        Bs[tt][n] = dtbc[(size_t)(c * CH + tt) * NCOMB + 48 + n];
    }
    __syncthreads();

    float Ad[DS], h[DS];
    #pragma unroll
    for (int n = 0; n < DS; ++n) {
        Ad[n] = -expf(alog[d * DS + n]);
        h[n] = 0.f;
    }

    size_t base = (size_t)(c * CH) * DI + d;
    float S = 0.f;
    for (int tt = 0; tt < CH; ++tt, base += DI) {
        const float dtv = dt[base];
        const float xv  = xcv[base];
        S += dtv;
        const float xdt = xv * dtv;
        #pragma unroll
        for (int n = 0; n < DS; ++n)
            h[n] = fmaf(h[n], __expf(Ad[n] * dtv), xdt * Bs[tt][n]);
    }

    const size_t o = ((size_t)c * DI + d) * DS;
    #pragma unroll
    for (int n = 0; n < DS; ++n) hloc[o + n] = h[n];
    Ssum[c * DI + d] = S;
}

__global__ __launch_bounds__(256)
void scan2_k(float* hc, const float* __restrict__ Ssum,
             const float* __restrict__ alog)
{
    const int p = blockIdx.x * 256 + threadIdx.x;
    if (p >= DI * DS) return;
    const int d = p >> 4;
    const float Ad = -expf(alog[p]);
    float h = 0.f;
    for (int c = 0; c < NC; ++c) {
        const size_t o = (size_t)c * DI * DS + p;
        const float hl = hc[o];
        hc[o] = h;
        h = fmaf(h, __expf(Ad * Ssum[c * DI + d]), hl);
    }
}

__global__ __launch_bounds__(256)
void scan3_k(float* dty, const float* __restrict__ xcv,
             const float* __restrict__ dtbc, const float* __restrict__ alog,
             const float* __restrict__ carry, const float* __restrict__ Dp,
             const float* __restrict__ xz)
{
    __shared__ float Bs[CH][DS];
    __shared__ float Cs[CH][DS];
    const int c = blockIdx.y;
    const int d = blockIdx.x * 256 + threadIdx.x;

    for (int i = threadIdx.x; i < CH * DS; i += 256) {
        int tt = i >> 4, n = i & 15;
        Bs[tt][n] = dtbc[(size_t)(c * CH + tt) * NCOMB + 48 + n];
        Cs[tt][n] = dtbc[(size_t)(c * CH + tt) * NCOMB + 64 + n];
    }
    __syncthreads();

    float Ad[DS], h[DS];
    const size_t co = ((size_t)c * DI + d) * DS;
    #pragma unroll
    for (int n = 0; n < DS; ++n) {
        Ad[n] = -expf(alog[d * DS + n]);
        h[n] = carry[co + n];
    }
    const float Dv = Dp[d];

    int t = c * CH;
    for (int tt = 0; tt < CH; ++tt, ++t) {
        const size_t o = (size_t)t * DI + d;
        const float dtv = dty[o];
        const float xv  = xcv[o];
        const float xdt = xv * dtv;
        float y = Dv * xv;
        #pragma unroll
        for (int n = 0; n < DS; ++n) {
            h[n] = fmaf(h[n], __expf(Ad[n] * dtv), xdt * Bs[tt][n]);
            y = fmaf(h[n], Cs[tt][n], y);
        }
        const float z = xz[(size_t)t * (2 * DI) + DI + d];
        dty[o] = y * silu_f(z);
    }
}

// ---------------------------------------------------------------------------
extern "C" void kernel_launch(void* const* d_in, const int* in_sizes, int n_in,
                              void* d_out, int out_size, void* d_ws, size_t ws_size,
                              hipStream_t stream)
{
    const float* u    = (const float*)d_in[0];
    const float* Wip  = (const float*)d_in[1];
    const float* cw   = (const float*)d_in[2];
    const float* cb   = (const float*)d_in[3];
    const float* xdt  = (const float*)d_in[4];
    const float* xbw  = (const float*)d_in[5];
    const float* xcw  = (const float*)d_in[6];
    const float* dtw  = (const float*)d_in[7];
    const float* dtb  = (const float*)d_in[8];
    const float* alog = (const float*)d_in[9];
    const float* Dp   = (const float*)d_in[10];
    const float* Wop  = (const float*)d_in[11];
    float* out = (float*)d_out;

    // workspace layout (floats) — 109 MB footprint (same as rounds 1-3)
    float* ws   = (float*)d_ws;
    float* xz   = ws;                                // L*2*DI
    float* xcv  = xz   + (size_t)L * 2 * DI;         // L*DI
    float* dtbc = xcv  + (size_t)L * DI;             // L*NCOMB
    float* dty  = dtbc + (size_t)L * NCOMB;          // L*DI
    float* Wt   = dty  + (size_t)L * DI;             // DI*NCOMB
    float* hc   = Wt   + (size_t)DI * NCOMB;         // NC*DI*DS
    float* Ssum = hc   + (size_t)NC * DI * DS;       // NC*DI

    // aliases into regions dead at time of use
    u16*   ubf  = (u16*)xcv;                         // [4096][768]  (dead after GEMM1)
    u16*   Wipb = (u16*)xcv + (size_t)L * DM;        // [3072][768]  (dead after GEMM1)
    float* g2p  = dty;                               // [16][4096][80] (dead after reduce)
    u16*   ybf  = (u16*)xz;                          // [4096][1536] (xz dead after scan3)
    u16*   wopb = (u16*)xz + (size_t)L * DI;         // [768][1536]

    const dim3 blk(256);

    // 1) early packs: ubf, Wipb (bf16), Wt (fp32 transposed proj weights)
    pack_early_k<<<(NU4 + NW4 + NWT + 255) / 256, blk, 0, stream>>>(
        u, Wip, xdt, xbw, xcw, ubf, Wipb, Wt);

    // 2) xz = u @ in_proj_w^T   [4096, 3072]  (plain bf16 MFMA, K=768)
    gemm_bf16_bt<<<dim3((2 * DI) / 128, L / 128), blk, 0, stream>>>(
        ubf, Wipb, xz, L, 2 * DI, DM);

    // 3) fused conv+SiLU + [dt_rank|B|C] split-K partials (writes xcv too)
    gemm2_conv_splitk<<<dim3(L / 64, G2_S), blk, 0, stream>>>(
        xz, cw, cb, Wt, xcv, g2p);
    gemm2_reduce<<<(L * NCOMB + 255) / 256, blk, 0, stream>>>(g2p, dtbc);

    // 4) dt = softplus(dt_rank @ dt_w^T + dt_b)  [4096, 1536] (overwrites g2p)
    gemm_f32<1><<<dim3(DI / 64, L / 64), blk, 0, stream>>>(
        dtbc, NCOMB, dtw, dtb, dty, L, DI, DR);

    // 5-7) chunked selective scan -> yz (in dty)
    scan1_k<<<dim3(DI / 256, NC), blk, 0, stream>>>(dty, xcv, dtbc, alog, hc, Ssum);
    scan2_k<<<(DI * DS) / 256, blk, 0, stream>>>(hc, Ssum, alog);
    scan3_k<<<dim3(DI / 256, NC), blk, 0, stream>>>(dty, xcv, dtbc, alog, hc, Dp, xz);

    // 8) late packs: ybf, wopb (xz region dead now)
    pack_late_k<<<(NY4 + NO4 + 255) / 256, blk, 0, stream>>>(dty, Wop, ybf, wopb);

    // 9) out = yz @ out_proj_w^T   [4096, 768]  (bf16 MFMA, 128x64 tile)
    gemm_bf16_bt_n64<<<dim3(DM / 64, L / 128), blk, 0, stream>>>(
        ybf, wopb, out, L, DM, DI);
}

// Round 5
// 266.287 us; speedup vs baseline: 2.6008x; 1.1258x over previous
//
#include <hip/hip_runtime.h>
#include <math.h>

// Problem constants (UnifiedMambaBlock, B=1)
#define L      4096
#define DM     768
#define DI     1536
#define DS     16
#define DR     48
#define NCOMB  80     // 48 dt_rank + 16 B + 16 C
#define CH     64     // scan chunk length
#define NC     64     // number of chunks (L / CH)
#define G2_S   16     // GEMM2 K-splits
#define G2_KC  96     // 1536 / 16
#define XZROW  6144   // xz row stride in u16 (3072 floats)

typedef unsigned short u16;
typedef unsigned int   u32;
typedef __attribute__((ext_vector_type(8))) short bf16x8;   // 8 bf16 = 4 VGPRs
typedef __attribute__((ext_vector_type(4))) float f32x4;

__device__ __forceinline__ float silu_f(float v) { return v / (1.f + __expf(-v)); }

__device__ __forceinline__ u16 f2bf(float f) {              // RNE f32 -> bf16
    u32 u = __float_as_uint(f);
    return (u16)((u + 0x7fffu + ((u >> 16) & 1u)) >> 16);
}

__device__ __forceinline__ void gl_lds16(const u16* g, u16* l) {
    __builtin_amdgcn_global_load_lds(
        (const __attribute__((address_space(1))) void*)g,
        (__attribute__((address_space(3))) void*)l, 16, 0, 0);
}

// ---------------------------------------------------------------------------
// bf16 MFMA GEMM (m97 structure): C[M,N] fp32 = A[M,K] @ W[N,K]^T, bf16 in.
// 128x128 tile, BK=32, 256 threads (4 waves, 2x2 of 64x64), double-buffer LDS.
// ---------------------------------------------------------------------------
__global__ __launch_bounds__(256)
void gemm_bf16_bt(const u16* __restrict__ A, const u16* __restrict__ W,
                  float* __restrict__ C, int M, int N, int K)
{
    __shared__ u16 As[2][128 * 32];
    __shared__ u16 Bs[2][128 * 32];

    const int tid  = threadIdx.x;
    const int lane = tid & 63;
    const int wave = tid >> 6;
    const int wr   = (wave >> 1) * 64;
    const int wc   = (wave & 1) * 64;
    const int m0   = blockIdx.y * 128;
    const int n0   = blockIdx.x * 128;

    const int r0 = tid >> 2;
    const int k0 = (tid & 3) * 8;

    const int frow = lane & 15;
    const int fk   = (lane >> 4) * 8;

    f32x4 acc[4][4];
    #pragma unroll
    for (int i = 0; i < 4; ++i)
        #pragma unroll
        for (int j = 0; j < 4; ++j)
            acc[i][j] = (f32x4){0.f, 0.f, 0.f, 0.f};

    const int NT = K >> 5;

#define STAGE(buf, kk) {                                                       \
        const u16* ga = A + (size_t)(m0 + r0) * K + (kk) + k0;                 \
        const u16* gw = W + (size_t)(n0 + r0) * K + (kk) + k0;                 \
        gl_lds16(ga,                   &As[buf][tid * 8]);                     \
        gl_lds16(ga + (size_t)64 * K,  &As[buf][2048 + tid * 8]);              \
        gl_lds16(gw,                   &Bs[buf][tid * 8]);                     \
        gl_lds16(gw + (size_t)64 * K,  &Bs[buf][2048 + tid * 8]); }

    STAGE(0, 0);
    __syncthreads();

    for (int t = 0; t < NT; ++t) {
        const int b = t & 1;
        if (t + 1 < NT) STAGE(b ^ 1, (t + 1) << 5);

        bf16x8 af[4], bw[4];
        #pragma unroll
        for (int m = 0; m < 4; ++m)
            af[m] = *(const bf16x8*)&As[b][(wr + m * 16 + frow) * 32 + fk];
        #pragma unroll
        for (int n = 0; n < 4; ++n)
            bw[n] = *(const bf16x8*)&Bs[b][(wc + n * 16 + frow) * 32 + fk];

        #pragma unroll
        for (int m = 0; m < 4; ++m)
            #pragma unroll
            for (int n = 0; n < 4; ++n)
                acc[m][n] = __builtin_amdgcn_mfma_f32_16x16x32_bf16(
                    af[m], bw[n], acc[m][n], 0, 0, 0);

        __syncthreads();
    }
#undef STAGE

    const int crow = (lane >> 4) * 4;
    const int ccol = lane & 15;
    #pragma unroll
    for (int m = 0; m < 4; ++m)
        #pragma unroll
        for (int n = 0; n < 4; ++n)
            #pragma unroll
            for (int r = 0; r < 4; ++r)
                C[(size_t)(m0 + wr + m * 16 + crow + r) * N
                  + n0 + wc + n * 16 + ccol] = acc[m][n][r];
}

// ---------------------------------------------------------------------------
// bf16 MFMA GEMM with strided rows (lda/ldw in u16 elems), 128(M)x64(N) tile.
// Used for GEMM4 where A (yz) and W (Wop) live in the dead x-half of xz rows.
// ---------------------------------------------------------------------------
__global__ __launch_bounds__(256)
void gemm_bf16_bt_n64(const u16* __restrict__ A, int lda,
                      const u16* __restrict__ W, int ldw,
                      float* __restrict__ C, int M, int N, int K)
{
    __shared__ u16 As[2][128 * 32];
    __shared__ u16 Bs[2][64 * 32];

    const int tid  = threadIdx.x;
    const int lane = tid & 63;
    const int wave = tid >> 6;
    const int wr   = (wave >> 1) * 64;
    const int wc   = (wave & 1) * 32;
    const int m0   = blockIdx.y * 128;
    const int n0   = blockIdx.x * 64;

    const int r0 = tid >> 2;
    const int k0 = (tid & 3) * 8;

    const int frow = lane & 15;
    const int fk   = (lane >> 4) * 8;

    f32x4 acc[4][2];
    #pragma unroll
    for (int i = 0; i < 4; ++i)
        #pragma unroll
        for (int j = 0; j < 2; ++j)
            acc[i][j] = (f32x4){0.f, 0.f, 0.f, 0.f};

    const int NT = K >> 5;

#define STG(buf, kk) {                                                         \
        const u16* ga = A + (size_t)(m0 + r0) * lda + (kk) + k0;               \
        gl_lds16(ga,                     &As[buf][tid * 8]);                   \
        gl_lds16(ga + (size_t)64 * lda,  &As[buf][2048 + tid * 8]);            \
        gl_lds16(W + (size_t)(n0 + r0) * ldw + (kk) + k0, &Bs[buf][tid * 8]); }

    STG(0, 0);
    __syncthreads();

    for (int t = 0; t < NT; ++t) {
        const int b = t & 1;
        if (t + 1 < NT) STG(b ^ 1, (t + 1) << 5);

        bf16x8 af[4], bw[2];
        #pragma unroll
        for (int m = 0; m < 4; ++m)
            af[m] = *(const bf16x8*)&As[b][(wr + m * 16 + frow) * 32 + fk];
        #pragma unroll
        for (int n = 0; n < 2; ++n)
            bw[n] = *(const bf16x8*)&Bs[b][(wc + n * 16 + frow) * 32 + fk];

        #pragma unroll
        for (int m = 0; m < 4; ++m)
            #pragma unroll
            for (int n = 0; n < 2; ++n)
                acc[m][n] = __builtin_amdgcn_mfma_f32_16x16x32_bf16(
                    af[m], bw[n], acc[m][n], 0, 0, 0);

        __syncthreads();
    }
#undef STG

    const int crow = (lane >> 4) * 4;
    const int ccol = lane & 15;
    #pragma unroll
    for (int m = 0; m < 4; ++m)
        #pragma unroll
        for (int n = 0; n < 2; ++n)
            #pragma unroll
            for (int r = 0; r < 4; ++r)
                C[(size_t)(m0 + wr + m * 16 + crow + r) * N
                  + n0 + wc + n * 16 + ccol] = acc[m][n][r];
}

// ---------------------------------------------------------------------------
// Early pack: u -> ubf (bf16), Wip -> Wipb (bf16), [xdt;xb;xc]^T -> Wt (fp32)
// ---------------------------------------------------------------------------
#define NU4  (L * DM / 4)            // 786432
#define NW4  (2 * DI * DM / 4)       // 589824
#define NWT  (DI * NCOMB)            // 122880
__global__ __launch_bounds__(256)
void pack_early_k(const float* __restrict__ u, const float* __restrict__ Wip,
                  const float* __restrict__ xdt, const float* __restrict__ xb,
                  const float* __restrict__ xc,
                  u16* __restrict__ ubf, u16* __restrict__ Wipb,
                  float* __restrict__ Wt)
{
    int i = blockIdx.x * 256 + threadIdx.x;
    if (i < NU4) {
        const float4 v = ((const float4*)u)[i];
        ushort4 o; o.x = f2bf(v.x); o.y = f2bf(v.y); o.z = f2bf(v.z); o.w = f2bf(v.w);
        ((ushort4*)ubf)[i] = o;
        return;
    }
    i -= NU4;
    if (i < NW4) {
        const float4 v = ((const float4*)Wip)[i];
        ushort4 o; o.x = f2bf(v.x); o.y = f2bf(v.y); o.z = f2bf(v.z); o.w = f2bf(v.w);
        ((ushort4*)Wipb)[i] = o;
        return;
    }
    i -= NW4;
    if (i < NWT) {
        const int k = i / NCOMB, n = i - k * NCOMB;
        float v;
        if (n < 48)      v = xdt[n * DI + k];
        else if (n < 64) v = xb[(n - 48) * DI + k];
        else             v = xc[(n - 64) * DI + k];
        Wt[i] = v;
    }
}

// ---------------------------------------------------------------------------
// Wop -> bf16, scattered into dead x-half of xz rows (row r, u16 cols 1536+c)
// ---------------------------------------------------------------------------
#define NO4  (DM * DI / 4)           // 294912
__global__ __launch_bounds__(256)
void pack_wop_k(const float* __restrict__ Wop, u16* __restrict__ xzu)
{
    int i = blockIdx.x * 256 + threadIdx.x;
    if (i >= NO4) return;
    const float4 v = ((const float4*)Wop)[i];
    ushort4 o; o.x = f2bf(v.x); o.y = f2bf(v.y); o.z = f2bf(v.z); o.w = f2bf(v.w);
    const int e = i * 4;
    const int r = e / DI, c = e - r * DI;
    *(ushort4*)(xzu + (size_t)r * XZROW + 1536 + c) = o;
}

// ---------------------------------------------------------------------------
// Vectorized causal depthwise conv (width 4) + bias + SiLU: 4 channels/thread
// ---------------------------------------------------------------------------
__global__ __launch_bounds__(256)
void conv_silu_v4(const float* __restrict__ xz, const float* __restrict__ cw,
                  const float* __restrict__ cb, float* __restrict__ xcv)
{
    int idx = blockIdx.x * 256 + threadIdx.x;
    if (idx >= L * (DI / 4)) return;
    const int t = idx / (DI / 4);
    const int q = idx - t * (DI / 4);
    const int d = q * 4;

    const float4 w0 = ((const float4*)cw)[d + 0];   // taps of channel d
    const float4 w1 = ((const float4*)cw)[d + 1];
    const float4 w2 = ((const float4*)cw)[d + 2];
    const float4 w3 = ((const float4*)cw)[d + 3];
    float4 acc = ((const float4*)cb)[q];

    const float* base = xz + d;
    #pragma unroll
    for (int j = 0; j < 4; ++j) {
        const int tt = t - 3 + j;
        if (tt >= 0) {
            const float4 x = *(const float4*)(base + (size_t)tt * (2 * DI));
            acc.x = fmaf(((const float*)&w0)[j], x.x, acc.x);
            acc.y = fmaf(((const float*)&w1)[j], x.y, acc.y);
            acc.z = fmaf(((const float*)&w2)[j], x.z, acc.z);
            acc.w = fmaf(((const float*)&w3)[j], x.w, acc.w);
        }
    }
    float4 o;
    o.x = silu_f(acc.x); o.y = silu_f(acc.y);
    o.z = silu_f(acc.z); o.w = silu_f(acc.w);
    ((float4*)xcv)[idx] = o;
}

// ---------------------------------------------------------------------------
// Generic fp32 GEMM (GEMM3 only). EPI 1: softplus(acc + bias[col])
// ---------------------------------------------------------------------------
template <int EPI>
__global__ __launch_bounds__(256)
void gemm_f32(const float* __restrict__ A, int lda,
              const float* __restrict__ W,
              const float* __restrict__ bias,
              float* __restrict__ C,
              int M, int N, int K)
{
    __shared__ float As[16][64];
    __shared__ float Ws[16][64];

    const int tid = threadIdx.x;
    const int tx = tid & 15;
    const int ty = tid >> 4;
    const int m0 = blockIdx.y * 64;
    const int n0 = blockIdx.x * 64;

    const int lrow = tid >> 2;
    const int lk   = (tid & 3) * 4;

    float acc[4][4] = {{0.f}};

    for (int kk = 0; kk < K; kk += 16) {
        {
            const float4 v = *(const float4*)(A + (size_t)(m0 + lrow) * lda + kk + lk);
            As[lk + 0][lrow] = v.x; As[lk + 1][lrow] = v.y;
            As[lk + 2][lrow] = v.z; As[lk + 3][lrow] = v.w;
        }
        {
            float4 v = make_float4(0.f, 0.f, 0.f, 0.f);
            if (n0 + lrow < N)
                v = *(const float4*)(W + (size_t)(n0 + lrow) * K + kk + lk);
            Ws[lk + 0][lrow] = v.x; Ws[lk + 1][lrow] = v.y;
            Ws[lk + 2][lrow] = v.z; Ws[lk + 3][lrow] = v.w;
        }
        __syncthreads();

        #pragma unroll
        for (int k = 0; k < 16; ++k) {
            const float4 av = *(const float4*)&As[k][ty * 4];
            const float4 bv = *(const float4*)&Ws[k][tx * 4];
            const float a[4] = {av.x, av.y, av.z, av.w};
            const float b[4] = {bv.x, bv.y, bv.z, bv.w};
            #pragma unroll
            for (int i = 0; i < 4; ++i)
                #pragma unroll
                for (int j = 0; j < 4; ++j)
                    acc[i][j] = fmaf(a[i], b[j], acc[i][j]);
        }
        __syncthreads();
    }

    const int col = n0 + tx * 4;
    if (col < N) {
        #pragma unroll
        for (int i = 0; i < 4; ++i) {
            const int row = m0 + ty * 4 + i;
            float4 v;
            float r[4];
            #pragma unroll
            for (int j = 0; j < 4; ++j) {
                float x = acc[i][j];
                if (EPI == 1) {
                    x += bias[col + j];
                    x = (x > 20.f) ? x : log1pf(expf(x));
                }
                r[j] = x;
            }
            v.x = r[0]; v.y = r[1]; v.z = r[2]; v.w = r[3];
            *(float4*)(C + (size_t)row * N + col) = v;
        }
    }
}

// ---------------------------------------------------------------------------
// GEMM2 split-K: part[s][L][80] = xcv[L][DI-slice] @ Wt[DI-slice][80]
// grid (64 M-tiles, 16 K-splits); whole chunk staged once, no inner barrier.
// ---------------------------------------------------------------------------
__global__ __launch_bounds__(256)
void gemm2_splitk(const float* __restrict__ A, const float* __restrict__ Wt,
                  float* __restrict__ part)
{
    __shared__ float As[G2_KC][65];     // +1 pad
    __shared__ float Ws[G2_KC][80];

    const int tid  = threadIdx.x;
    const int m0   = blockIdx.x * 64;
    const int koff = blockIdx.y * G2_KC;

    // stage A: 64 rows x 96 k, k-major in LDS (float4 coalesced from xcv)
    {
        const int r = tid >> 2, cg = tid & 3;
        #pragma unroll
        for (int j = 0; j < 6; ++j) {
            const int kk = (j * 4 + cg) * 4;
            const float4 v = *(const float4*)(A + (size_t)(m0 + r) * DI + koff + kk);
            As[kk + 0][r] = v.x; As[kk + 1][r] = v.y;
            As[kk + 2][r] = v.z; As[kk + 3][r] = v.w;
        }
    }
    // stage W: 96 k x 80 n (Wt is k-major, coalesced)
    for (int i = tid; i < G2_KC * 80; i += 256)
        (&Ws[0][0])[i] = Wt[(size_t)koff * 80 + i];
    __syncthreads();

    const int g  = tid >> 6;    // wave -> 20-col strip
    const int r  = tid & 63;    // lane -> row
    const int c0 = g * 20;

    float acc[20];
    #pragma unroll
    for (int j = 0; j < 20; ++j) acc[j] = 0.f;

    #pragma unroll 2
    for (int k = 0; k < G2_KC; ++k) {
        const float a = As[k][r];
        #pragma unroll
        for (int q = 0; q < 5; ++q) {
            const float4 w = *(const float4*)&Ws[k][c0 + q * 4];
            acc[q * 4 + 0] = fmaf(a, w.x, acc[q * 4 + 0]);
            acc[q * 4 + 1] = fmaf(a, w.y, acc[q * 4 + 1]);
            acc[q * 4 + 2] = fmaf(a, w.z, acc[q * 4 + 2]);
            acc[q * 4 + 3] = fmaf(a, w.w, acc[q * 4 + 3]);
        }
    }

    float* p = part + (size_t)blockIdx.y * (L * NCOMB)
                    + (size_t)(m0 + r) * NCOMB + c0;
    #pragma unroll
    for (int q = 0; q < 5; ++q)
        ((float4*)p)[q] = make_float4(acc[q * 4], acc[q * 4 + 1],
                                      acc[q * 4 + 2], acc[q * 4 + 3]);
}

__global__ __launch_bounds__(256)
void gemm2_reduce(const float* __restrict__ part, float* __restrict__ dtbc)
{
    int i = blockIdx.x * 256 + threadIdx.x;
    if (i >= L * NCOMB) return;
    float s = 0.f;
    #pragma unroll
    for (int j = 0; j < G2_S; ++j)
        s += part[(size_t)j * L * NCOMB + i];
    dtbc[i] = s;
}

// ---------------------------------------------------------------------------
__global__ __launch_bounds__(256)
void scan1_k(const float* __restrict__ dt, const float* __restrict__ xcv,
             const float* __restrict__ dtbc, const float* __restrict__ alog,
             float* __restrict__ hloc, float* __restrict__ Ssum)
{
    __shared__ float Bs[CH][DS];
    const int c = blockIdx.y;
    const int d = blockIdx.x * 256 + threadIdx.x;

    for (int i = threadIdx.x; i < CH * DS; i += 256) {
        int tt = i >> 4, n = i & 15;
        Bs[tt][n] = dtbc[(size_t)(c * CH + tt) * NCOMB + 48 + n];
    }
    __syncthreads();

    float Ad[DS], h[DS];
    #pragma unroll
    for (int n = 0; n < DS; ++n) {
        Ad[n] = -expf(alog[d * DS + n]);
        h[n] = 0.f;
    }

    size_t base = (size_t)(c * CH) * DI + d;
    float S = 0.f;
    for (int tt = 0; tt < CH; ++tt, base += DI) {
        const float dtv = dt[base];
        const float xv  = xcv[base];
        S += dtv;
        const float xdt = xv * dtv;
        #pragma unroll
        for (int n = 0; n < DS; ++n)
            h[n] = fmaf(h[n], __expf(Ad[n] * dtv), xdt * Bs[tt][n]);
    }

    const size_t o = ((size_t)c * DI + d) * DS;
    #pragma unroll
    for (int n = 0; n < DS; ++n) hloc[o + n] = h[n];
    Ssum[c * DI + d] = S;
}

__global__ __launch_bounds__(256)
void scan2_k(float* hc, const float* __restrict__ Ssum,
             const float* __restrict__ alog)
{
    const int p = blockIdx.x * 256 + threadIdx.x;
    if (p >= DI * DS) return;
    const int d = p >> 4;
    const float Ad = -expf(alog[p]);
    float h = 0.f;
    for (int c = 0; c < NC; ++c) {
        const size_t o = (size_t)c * DI * DS + p;
        const float hl = hc[o];
        hc[o] = h;
        h = fmaf(h, __expf(Ad * Ssum[c * DI + d]), hl);
    }
}

// ---------------------------------------------------------------------------
// Scan pass 3: replay with carry-in; emit yz as bf16 into the dead x-half of
// xz rows (u16 col d of row t, stride XZROW). z is read from the z-half.
// ---------------------------------------------------------------------------
__global__ __launch_bounds__(256)
void scan3_k(const float* __restrict__ dt, const float* __restrict__ xcv,
             const float* __restrict__ dtbc, const float* __restrict__ alog,
             const float* __restrict__ carry, const float* __restrict__ Dp,
             const float* __restrict__ xz, u16* __restrict__ ybf)
{
    __shared__ float Bs[CH][DS];
    __shared__ float Cs[CH][DS];
    const int c = blockIdx.y;
    const int d = blockIdx.x * 256 + threadIdx.x;

    for (int i = threadIdx.x; i < CH * DS; i += 256) {
        int tt = i >> 4, n = i & 15;
        Bs[tt][n] = dtbc[(size_t)(c * CH + tt) * NCOMB + 48 + n];
        Cs[tt][n] = dtbc[(size_t)(c * CH + tt) * NCOMB + 64 + n];
    }
    __syncthreads();

    float Ad[DS], h[DS];
    const size_t co = ((size_t)c * DI + d) * DS;
    #pragma unroll
    for (int n = 0; n < DS; ++n) {
        Ad[n] = -expf(alog[d * DS + n]);
        h[n] = carry[co + n];
    }
    const float Dv = Dp[d];

    int t = c * CH;
    for (int tt = 0; tt < CH; ++tt, ++t) {
        const size_t o = (size_t)t * DI + d;
        const float dtv = dt[o];
        const float xv  = xcv[o];
        const float xdt = xv * dtv;
        float y = Dv * xv;
        #pragma unroll
        for (int n = 0; n < DS; ++n) {
            h[n] = fmaf(h[n], __expf(Ad[n] * dtv), xdt * Bs[tt][n]);
            y = fmaf(h[n], Cs[tt][n], y);
        }
        const float z = xz[(size_t)t * (2 * DI) + DI + d];
        ybf[(size_t)t * XZROW + d] = f2bf(y * silu_f(z));
    }
}

// ---------------------------------------------------------------------------
extern "C" void kernel_launch(void* const* d_in, const int* in_sizes, int n_in,
                              void* d_out, int out_size, void* d_ws, size_t ws_size,
                              hipStream_t stream)
{
    const float* u    = (const float*)d_in[0];
    const float* Wip  = (const float*)d_in[1];
    const float* cw   = (const float*)d_in[2];
    const float* cb   = (const float*)d_in[3];
    const float* xdt  = (const float*)d_in[4];
    const float* xbw  = (const float*)d_in[5];
    const float* xcw  = (const float*)d_in[6];
    const float* dtw  = (const float*)d_in[7];
    const float* dtb  = (const float*)d_in[8];
    const float* alog = (const float*)d_in[9];
    const float* Dp   = (const float*)d_in[10];
    const float* Wop  = (const float*)d_in[11];
    float* out = (float*)d_out;

    // workspace layout (floats) — 109 MB footprint (unchanged since round 1)
    float* ws   = (float*)d_ws;
    float* xz   = ws;                                // L*2*DI
    float* xcv  = xz   + (size_t)L * 2 * DI;         // L*DI
    float* dtbc = xcv  + (size_t)L * DI;             // L*NCOMB
    float* dty  = dtbc + (size_t)L * NCOMB;          // L*DI (dt)
    float* Wt   = dty  + (size_t)L * DI;             // DI*NCOMB
    float* hc   = Wt   + (size_t)DI * NCOMB;         // NC*DI*DS
    float* Ssum = hc   + (size_t)NC * DI * DS;       // NC*DI

    // aliases into regions dead at time of use
    u16*   ubf  = (u16*)xcv;                   // [4096][768]  (dead after GEMM1)
    u16*   Wipb = (u16*)xcv + (size_t)L * DM;  // [3072][768]  (dead after GEMM1)
    float* g2p  = dty;                         // [16][4096][80] (dead after reduce)
    u16*   xzu  = (u16*)xz;                    // xz as u16; x-half dead after conv:
                                               //   ybf  = rows t, cols [0,1536)
                                               //   wopb = rows r<768, cols [1536,3072)

    const dim3 blk(256);

    // 1) early packs: ubf, Wipb (bf16), Wt (fp32 transposed proj weights)
    pack_early_k<<<(NU4 + NW4 + NWT + 255) / 256, blk, 0, stream>>>(
        u, Wip, xdt, xbw, xcw, ubf, Wipb, Wt);

    // 2) xz = u @ in_proj_w^T   [4096, 3072]  (bf16 MFMA, K=768)
    gemm_bf16_bt<<<dim3((2 * DI) / 128, L / 128), blk, 0, stream>>>(
        ubf, Wipb, xz, L, 2 * DI, DM);

    // 3) causal conv + SiLU -> xcv (vectorized, 4 ch/thread)
    conv_silu_v4<<<(L * (DI / 4) + 255) / 256, blk, 0, stream>>>(xz, cw, cb, xcv);

    // 4) Wop -> bf16 into dead x-half of xz (after conv has consumed x)
    pack_wop_k<<<(NO4 + 255) / 256, blk, 0, stream>>>(Wop, xzu);

    // 5) [dt_rank|B|C] = xcv @ Wt via split-K (partials in dead dty region)
    gemm2_splitk<<<dim3(L / 64, G2_S), blk, 0, stream>>>(xcv, Wt, g2p);
    gemm2_reduce<<<(L * NCOMB + 255) / 256, blk, 0, stream>>>(g2p, dtbc);

    // 6) dt = softplus(dt_rank @ dt_w^T + dt_b)  [4096, 1536] (overwrites g2p)
    gemm_f32<1><<<dim3(DI / 64, L / 64), blk, 0, stream>>>(
        dtbc, NCOMB, dtw, dtb, dty, L, DI, DR);

    // 7-9) chunked selective scan; scan3 emits yz as bf16 into xz x-half
    scan1_k<<<dim3(DI / 256, NC), blk, 0, stream>>>(dty, xcv, dtbc, alog, hc, Ssum);
    scan2_k<<<(DI * DS) / 256, blk, 0, stream>>>(hc, Ssum, alog);
    scan3_k<<<dim3(DI / 256, NC), blk, 0, stream>>>(
        dty, xcv, dtbc, alog, hc, Dp, xz, xzu);

    // 10) out = yz @ out_proj_w^T   [4096, 768]  (bf16 MFMA, strided rows)
    gemm_bf16_bt_n64<<<dim3(DM / 64, L / 128), blk, 0, stream>>>(
        xzu, XZROW, xzu + 1536, XZROW, out, L, DM, DI);
}

// Round 6
// 240.160 us; speedup vs baseline: 2.8837x; 1.1088x over previous
//
#include <hip/hip_runtime.h>
#include <math.h>

// Problem constants (UnifiedMambaBlock, B=1)
#define L      4096
#define DM     768
#define DI     1536
#define DS     16
#define DR     48
#define NCOMB  80     // 48 dt_rank + 16 B + 16 C
#define CH     32     // scan chunk length
#define NC     128    // number of chunks (L / CH)
#define G2_S   16     // GEMM2 K-splits
#define G2_KC  96     // 1536 / 16
#define XZROW  6144   // xz row stride in u16 (3072 floats)

typedef unsigned short u16;
typedef unsigned int   u32;
typedef __attribute__((ext_vector_type(8))) short bf16x8;   // 8 bf16 = 4 VGPRs
typedef __attribute__((ext_vector_type(4))) float f32x4;

__device__ __forceinline__ float silu_f(float v) { return v / (1.f + __expf(-v)); }

__device__ __forceinline__ u16 f2bf(float f) {              // RNE f32 -> bf16
    u32 u = __float_as_uint(f);
    return (u16)((u + 0x7fffu + ((u >> 16) & 1u)) >> 16);
}
__device__ __forceinline__ float bf2f(u16 h) {
    return __uint_as_float(((u32)h) << 16);
}

__device__ __forceinline__ void gl_lds16(const u16* g, u16* l) {
    __builtin_amdgcn_global_load_lds(
        (const __attribute__((address_space(1))) void*)g,
        (__attribute__((address_space(3))) void*)l, 16, 0, 0);
}

// ---------------------------------------------------------------------------
// bf16 MFMA GEMM (m97 structure): C[M,N] fp32 = A[M,K] @ W[N,K]^T, bf16 in.
// 128x128 tile, BK=32, 256 threads (4 waves, 2x2 of 64x64), double-buffer LDS.
// ---------------------------------------------------------------------------
__global__ __launch_bounds__(256)
void gemm_bf16_bt(const u16* __restrict__ A, const u16* __restrict__ W,
                  float* __restrict__ C, int M, int N, int K)
{
    __shared__ u16 As[2][128 * 32];
    __shared__ u16 Bs[2][128 * 32];

    const int tid  = threadIdx.x;
    const int lane = tid & 63;
    const int wave = tid >> 6;
    const int wr   = (wave >> 1) * 64;
    const int wc   = (wave & 1) * 64;
    const int m0   = blockIdx.y * 128;
    const int n0   = blockIdx.x * 128;

    const int r0 = tid >> 2;
    const int k0 = (tid & 3) * 8;

    const int frow = lane & 15;
    const int fk   = (lane >> 4) * 8;

    f32x4 acc[4][4];
    #pragma unroll
    for (int i = 0; i < 4; ++i)
        #pragma unroll
        for (int j = 0; j < 4; ++j)
            acc[i][j] = (f32x4){0.f, 0.f, 0.f, 0.f};

    const int NT = K >> 5;

#define STAGE(buf, kk) {                                                       \
        const u16* ga = A + (size_t)(m0 + r0) * K + (kk) + k0;                 \
        const u16* gw = W + (size_t)(n0 + r0) * K + (kk) + k0;                 \
        gl_lds16(ga,                   &As[buf][tid * 8]);                     \
        gl_lds16(ga + (size_t)64 * K,  &As[buf][2048 + tid * 8]);              \
        gl_lds16(gw,                   &Bs[buf][tid * 8]);                     \
        gl_lds16(gw + (size_t)64 * K,  &Bs[buf][2048 + tid * 8]); }

    STAGE(0, 0);
    __syncthreads();

    for (int t = 0; t < NT; ++t) {
        const int b = t & 1;
        if (t + 1 < NT) STAGE(b ^ 1, (t + 1) << 5);

        bf16x8 af[4], bw[4];
        #pragma unroll
        for (int m = 0; m < 4; ++m)
            af[m] = *(const bf16x8*)&As[b][(wr + m * 16 + frow) * 32 + fk];
        #pragma unroll
        for (int n = 0; n < 4; ++n)
            bw[n] = *(const bf16x8*)&Bs[b][(wc + n * 16 + frow) * 32 + fk];

        #pragma unroll
        for (int m = 0; m < 4; ++m)
            #pragma unroll
            for (int n = 0; n < 4; ++n)
                acc[m][n] = __builtin_amdgcn_mfma_f32_16x16x32_bf16(
                    af[m], bw[n], acc[m][n], 0, 0, 0);

        __syncthreads();
    }
#undef STAGE

    const int crow = (lane >> 4) * 4;
    const int ccol = lane & 15;
    #pragma unroll
    for (int m = 0; m < 4; ++m)
        #pragma unroll
        for (int n = 0; n < 4; ++n)
            #pragma unroll
            for (int r = 0; r < 4; ++r)
                C[(size_t)(m0 + wr + m * 16 + crow + r) * N
                  + n0 + wc + n * 16 + ccol] = acc[m][n][r];
}

// ---------------------------------------------------------------------------
// bf16 MFMA GEMM with strided rows (lda/ldw in u16 elems), 128(M)x64(N) tile.
// ---------------------------------------------------------------------------
__global__ __launch_bounds__(256)
void gemm_bf16_bt_n64(const u16* __restrict__ A, int lda,
                      const u16* __restrict__ W, int ldw,
                      float* __restrict__ C, int M, int N, int K)
{
    __shared__ u16 As[2][128 * 32];
    __shared__ u16 Bs[2][64 * 32];

    const int tid  = threadIdx.x;
    const int lane = tid & 63;
    const int wave = tid >> 6;
    const int wr   = (wave >> 1) * 64;
    const int wc   = (wave & 1) * 32;
    const int m0   = blockIdx.y * 128;
    const int n0   = blockIdx.x * 64;

    const int r0 = tid >> 2;
    const int k0 = (tid & 3) * 8;

    const int frow = lane & 15;
    const int fk   = (lane >> 4) * 8;

    f32x4 acc[4][2];
    #pragma unroll
    for (int i = 0; i < 4; ++i)
        #pragma unroll
        for (int j = 0; j < 2; ++j)
            acc[i][j] = (f32x4){0.f, 0.f, 0.f, 0.f};

    const int NT = K >> 5;

#define STG(buf, kk) {                                                         \
        const u16* ga = A + (size_t)(m0 + r0) * lda + (kk) + k0;               \
        gl_lds16(ga,                     &As[buf][tid * 8]);                   \
        gl_lds16(ga + (size_t)64 * lda,  &As[buf][2048 + tid * 8]);            \
        gl_lds16(W + (size_t)(n0 + r0) * ldw + (kk) + k0, &Bs[buf][tid * 8]); }

    STG(0, 0);
    __syncthreads();

    for (int t = 0; t < NT; ++t) {
        const int b = t & 1;
        if (t + 1 < NT) STG(b ^ 1, (t + 1) << 5);

        bf16x8 af[4], bw[2];
        #pragma unroll
        for (int m = 0; m < 4; ++m)
            af[m] = *(const bf16x8*)&As[b][(wr + m * 16 + frow) * 32 + fk];
        #pragma unroll
        for (int n = 0; n < 2; ++n)
            bw[n] = *(const bf16x8*)&Bs[b][(wc + n * 16 + frow) * 32 + fk];

        #pragma unroll
        for (int m = 0; m < 4; ++m)
            #pragma unroll
            for (int n = 0; n < 2; ++n)
                acc[m][n] = __builtin_amdgcn_mfma_f32_16x16x32_bf16(
                    af[m], bw[n], acc[m][n], 0, 0, 0);

        __syncthreads();
    }
#undef STG

    const int crow = (lane >> 4) * 4;
    const int ccol = lane & 15;
    #pragma unroll
    for (int m = 0; m < 4; ++m)
        #pragma unroll
        for (int n = 0; n < 2; ++n)
            #pragma unroll
            for (int r = 0; r < 4; ++r)
                C[(size_t)(m0 + wr + m * 16 + crow + r) * N
                  + n0 + wc + n * 16 + ccol] = acc[m][n][r];
}

// ---------------------------------------------------------------------------
// Early pack: u -> ubf (bf16), Wip -> Wipb (bf16), [xdt;xb;xc]^T -> Wt (fp32)
// ---------------------------------------------------------------------------
#define NU4  (L * DM / 4)            // 786432
#define NW4  (2 * DI * DM / 4)       // 589824
#define NWT  (DI * NCOMB)            // 122880
__global__ __launch_bounds__(256)
void pack_early_k(const float* __restrict__ u, const float* __restrict__ Wip,
                  const float* __restrict__ xdt, const float* __restrict__ xb,
                  const float* __restrict__ xc,
                  u16* __restrict__ ubf, u16* __restrict__ Wipb,
                  float* __restrict__ Wt)
{
    int i = blockIdx.x * 256 + threadIdx.x;
    if (i < NU4) {
        const float4 v = ((const float4*)u)[i];
        ushort4 o; o.x = f2bf(v.x); o.y = f2bf(v.y); o.z = f2bf(v.z); o.w = f2bf(v.w);
        ((ushort4*)ubf)[i] = o;
        return;
    }
    i -= NU4;
    if (i < NW4) {
        const float4 v = ((const float4*)Wip)[i];
        ushort4 o; o.x = f2bf(v.x); o.y = f2bf(v.y); o.z = f2bf(v.z); o.w = f2bf(v.w);
        ((ushort4*)Wipb)[i] = o;
        return;
    }
    i -= NW4;
    if (i < NWT) {
        const int k = i / NCOMB, n = i - k * NCOMB;
        float v;
        if (n < 48)      v = xdt[n * DI + k];
        else if (n < 64) v = xb[(n - 48) * DI + k];
        else             v = xc[(n - 64) * DI + k];
        Wt[i] = v;
    }
}

// ---------------------------------------------------------------------------
// Wop -> bf16, scattered into dead x-half of xz rows (row r, u16 cols 1536+c)
// ---------------------------------------------------------------------------
#define NO4  (DM * DI / 4)           // 294912
__global__ __launch_bounds__(256)
void pack_wop_k(const float* __restrict__ Wop, u16* __restrict__ xzu)
{
    int i = blockIdx.x * 256 + threadIdx.x;
    if (i >= NO4) return;
    const float4 v = ((const float4*)Wop)[i];
    ushort4 o; o.x = f2bf(v.x); o.y = f2bf(v.y); o.z = f2bf(v.z); o.w = f2bf(v.w);
    const int e = i * 4;
    const int r = e / DI, c = e - r * DI;
    *(ushort4*)(xzu + (size_t)r * XZROW + 1536 + c) = o;
}

// ---------------------------------------------------------------------------
// Vectorized causal depthwise conv (width 4) + bias + SiLU: 4 channels/thread
// ---------------------------------------------------------------------------
__global__ __launch_bounds__(256)
void conv_silu_v4(const float* __restrict__ xz, const float* __restrict__ cw,
                  const float* __restrict__ cb, float* __restrict__ xcv)
{
    int idx = blockIdx.x * 256 + threadIdx.x;
    if (idx >= L * (DI / 4)) return;
    const int t = idx / (DI / 4);
    const int q = idx - t * (DI / 4);
    const int d = q * 4;

    const float4 w0 = ((const float4*)cw)[d + 0];
    const float4 w1 = ((const float4*)cw)[d + 1];
    const float4 w2 = ((const float4*)cw)[d + 2];
    const float4 w3 = ((const float4*)cw)[d + 3];
    float4 acc = ((const float4*)cb)[q];

    const float* base = xz + d;
    #pragma unroll
    for (int j = 0; j < 4; ++j) {
        const int tt = t - 3 + j;
        if (tt >= 0) {
            const float4 x = *(const float4*)(base + (size_t)tt * (2 * DI));
            acc.x = fmaf(((const float*)&w0)[j], x.x, acc.x);
            acc.y = fmaf(((const float*)&w1)[j], x.y, acc.y);
            acc.z = fmaf(((const float*)&w2)[j], x.z, acc.z);
            acc.w = fmaf(((const float*)&w3)[j], x.w, acc.w);
        }
    }
    float4 o;
    o.x = silu_f(acc.x); o.y = silu_f(acc.y);
    o.z = silu_f(acc.z); o.w = silu_f(acc.w);
    ((float4*)xcv)[idx] = o;
}

// ---------------------------------------------------------------------------
// GEMM2 split-K: part[s][L][80] = xcv[L][DI-slice] @ Wt[DI-slice][80]
// ---------------------------------------------------------------------------
__global__ __launch_bounds__(256)
void gemm2_splitk(const float* __restrict__ A, const float* __restrict__ Wt,
                  float* __restrict__ part)
{
    __shared__ float As[G2_KC][65];     // +1 pad
    __shared__ float Ws[G2_KC][80];

    const int tid  = threadIdx.x;
    const int m0   = blockIdx.x * 64;
    const int koff = blockIdx.y * G2_KC;

    {
        const int r = tid >> 2, cg = tid & 3;
        #pragma unroll
        for (int j = 0; j < 6; ++j) {
            const int kk = (j * 4 + cg) * 4;
            const float4 v = *(const float4*)(A + (size_t)(m0 + r) * DI + koff + kk);
            As[kk + 0][r] = v.x; As[kk + 1][r] = v.y;
            As[kk + 2][r] = v.z; As[kk + 3][r] = v.w;
        }
    }
    for (int i = tid; i < G2_KC * 80; i += 256)
        (&Ws[0][0])[i] = Wt[(size_t)koff * 80 + i];
    __syncthreads();

    const int g  = tid >> 6;
    const int r  = tid & 63;
    const int c0 = g * 20;

    float acc[20];
    #pragma unroll
    for (int j = 0; j < 20; ++j) acc[j] = 0.f;

    #pragma unroll 2
    for (int k = 0; k < G2_KC; ++k) {
        const float a = As[k][r];
        #pragma unroll
        for (int q = 0; q < 5; ++q) {
            const float4 w = *(const float4*)&Ws[k][c0 + q * 4];
            acc[q * 4 + 0] = fmaf(a, w.x, acc[q * 4 + 0]);
            acc[q * 4 + 1] = fmaf(a, w.y, acc[q * 4 + 1]);
            acc[q * 4 + 2] = fmaf(a, w.z, acc[q * 4 + 2]);
            acc[q * 4 + 3] = fmaf(a, w.w, acc[q * 4 + 3]);
        }
    }

    float* p = part + (size_t)blockIdx.y * (L * NCOMB)
                    + (size_t)(m0 + r) * NCOMB + c0;
    #pragma unroll
    for (int q = 0; q < 5; ++q)
        ((float4*)p)[q] = make_float4(acc[q * 4], acc[q * 4 + 1],
                                      acc[q * 4 + 2], acc[q * 4 + 3]);
}

__global__ __launch_bounds__(256)
void gemm2_reduce(const float* __restrict__ part, float* __restrict__ dtbc)
{
    int i = blockIdx.x * 256 + threadIdx.x;
    if (i >= L * NCOMB) return;
    float s = 0.f;
    #pragma unroll
    for (int j = 0; j < G2_S; ++j)
        s += part[(size_t)j * L * NCOMB + i];
    dtbc[i] = s;
}

// ---------------------------------------------------------------------------
// dt = softplus(dtr @ dtw^T + dtb): block = 256 channels x 32 timesteps.
// dtw row in registers, dtr tile in LDS (broadcast reads), coalesced stores.
// ---------------------------------------------------------------------------
__global__ __launch_bounds__(256)
void dt_k(const float* __restrict__ dtbc, const float* __restrict__ dtw,
          const float* __restrict__ dtb, float* __restrict__ dt)
{
    __shared__ float dtr_s[32][48];
    const int tid = threadIdx.x;
    const int d   = blockIdx.x * 256 + tid;
    const int t0  = blockIdx.y * 32;

    // stage dtr tile: 32 rows x 48 cols = 384 float4s
    for (int i = tid; i < 384; i += 256) {
        const int r = i / 12, c = (i - r * 12) * 4;
        const float4 v = *(const float4*)(dtbc + (size_t)(t0 + r) * NCOMB + c);
        *(float4*)&dtr_s[r][c] = v;
    }
    __syncthreads();

    float w[48];
    #pragma unroll
    for (int j = 0; j < 12; ++j) {
        const float4 v = *(const float4*)(dtw + (size_t)d * DR + j * 4);
        w[j * 4 + 0] = v.x; w[j * 4 + 1] = v.y;
        w[j * 4 + 2] = v.z; w[j * 4 + 3] = v.w;
    }
    const float b = dtb[d];

    for (int t = 0; t < 32; ++t) {
        float s = b;
        #pragma unroll
        for (int j = 0; j < 12; ++j) {
            const float4 v = *(const float4*)&dtr_s[t][j * 4];
            s = fmaf(v.x, w[j * 4 + 0], s);
            s = fmaf(v.y, w[j * 4 + 1], s);
            s = fmaf(v.z, w[j * 4 + 2], s);
            s = fmaf(v.w, w[j * 4 + 3], s);
        }
        dt[(size_t)(t0 + t) * DI + d] = (s > 20.f) ? s : log1pf(expf(s));
    }
}

// ---------------------------------------------------------------------------
// Scan pass 1: per-chunk local states (bf16) + dt chunk-sums.
// ---------------------------------------------------------------------------
__global__ __launch_bounds__(256)
void scan1_k(const float* __restrict__ dt, const float* __restrict__ xcv,
             const float* __restrict__ dtbc, const float* __restrict__ alog,
             u16* __restrict__ hloc, float* __restrict__ Ssum)
{
    __shared__ float Bs[CH][DS];
    const int c = blockIdx.y;
    const int d = blockIdx.x * 256 + threadIdx.x;

    for (int i = threadIdx.x; i < CH * DS; i += 256) {
        int tt = i >> 4, n = i & 15;
        Bs[tt][n] = dtbc[(size_t)(c * CH + tt) * NCOMB + 48 + n];
    }
    __syncthreads();

    float Ad[DS], h[DS];
    #pragma unroll
    for (int n = 0; n < DS; ++n) {
        Ad[n] = -expf(alog[d * DS + n]);
        h[n] = 0.f;
    }

    size_t base = (size_t)(c * CH) * DI + d;
    float S = 0.f;
    for (int tt = 0; tt < CH; ++tt, base += DI) {
        const float dtv = dt[base];
        const float xv  = xcv[base];
        S += dtv;
        const float xdt = xv * dtv;
        #pragma unroll
        for (int n = 0; n < DS; ++n)
            h[n] = fmaf(h[n], __expf(Ad[n] * dtv), xdt * Bs[tt][n]);
    }

    u16* o = hloc + ((size_t)c * DI + d) * DS;
    #pragma unroll
    for (int q = 0; q < 4; ++q) {
        ushort4 pk;
        pk.x = f2bf(h[q * 4 + 0]); pk.y = f2bf(h[q * 4 + 1]);
        pk.z = f2bf(h[q * 4 + 2]); pk.w = f2bf(h[q * 4 + 3]);
        *(ushort4*)(o + q * 4) = pk;
    }
    Ssum[c * DI + d] = S;
}

// ---------------------------------------------------------------------------
// Scan pass 2: scan the NC chunk carries per (d,n); hc bf16 in-place.
// ---------------------------------------------------------------------------
__global__ __launch_bounds__(256)
void scan2_k(u16* hc, const float* __restrict__ Ssum,
             const float* __restrict__ alog)
{
    const int p = blockIdx.x * 256 + threadIdx.x;
    if (p >= DI * DS) return;
    const int d = p >> 4;
    const float Ad = -expf(alog[p]);
    float h = 0.f;
    for (int c = 0; c < NC; ++c) {
        const size_t o = (size_t)c * DI * DS + p;
        const float hl = bf2f(hc[o]);     // local state
        hc[o] = f2bf(h);                  // overwrite with carry-in
        h = fmaf(h, __expf(Ad * Ssum[c * DI + d]), hl);
    }
}

// ---------------------------------------------------------------------------
// Scan pass 3: replay with carry-in; emit yz bf16 into dead x-half of xz.
// ---------------------------------------------------------------------------
__global__ __launch_bounds__(256)
void scan3_k(const float* __restrict__ dt, const float* __restrict__ xcv,
             const float* __restrict__ dtbc, const float* __restrict__ alog,
             const u16* __restrict__ carry, const float* __restrict__ Dp,
             const float* __restrict__ xz, u16* __restrict__ ybf)
{
    __shared__ float Bs[CH][DS];
    __shared__ float Cs[CH][DS];
    const int c = blockIdx.y;
    const int d = blockIdx.x * 256 + threadIdx.x;

    for (int i = threadIdx.x; i < CH * DS; i += 256) {
        int tt = i >> 4, n = i & 15;
        Bs[tt][n] = dtbc[(size_t)(c * CH + tt) * NCOMB + 48 + n];
        Cs[tt][n] = dtbc[(size_t)(c * CH + tt) * NCOMB + 64 + n];
    }
    __syncthreads();

    float Ad[DS], h[DS];
    const u16* co = carry + ((size_t)c * DI + d) * DS;
    #pragma unroll
    for (int q = 0; q < 4; ++q) {
        const ushort4 cv = *(const ushort4*)(co + q * 4);
        h[q * 4 + 0] = bf2f(cv.x); h[q * 4 + 1] = bf2f(cv.y);
        h[q * 4 + 2] = bf2f(cv.z); h[q * 4 + 3] = bf2f(cv.w);
    }
    #pragma unroll
    for (int n = 0; n < DS; ++n)
        Ad[n] = -expf(alog[d * DS + n]);
    const float Dv = Dp[d];

    int t = c * CH;
    for (int tt = 0; tt < CH; ++tt, ++t) {
        const size_t o = (size_t)t * DI + d;
        const float dtv = dt[o];
        const float xv  = xcv[o];
        const float xdt = xv * dtv;
        float y = Dv * xv;
        #pragma unroll
        for (int n = 0; n < DS; ++n) {
            h[n] = fmaf(h[n], __expf(Ad[n] * dtv), xdt * Bs[tt][n]);
            y = fmaf(h[n], Cs[tt][n], y);
        }
        const float z = xz[(size_t)t * (2 * DI) + DI + d];
        ybf[(size_t)t * XZROW + d] = f2bf(y * silu_f(z));
    }
}

// ---------------------------------------------------------------------------
extern "C" void kernel_launch(void* const* d_in, const int* in_sizes, int n_in,
                              void* d_out, int out_size, void* d_ws, size_t ws_size,
                              hipStream_t stream)
{
    const float* u    = (const float*)d_in[0];
    const float* Wip  = (const float*)d_in[1];
    const float* cw   = (const float*)d_in[2];
    const float* cb   = (const float*)d_in[3];
    const float* xdt  = (const float*)d_in[4];
    const float* xbw  = (const float*)d_in[5];
    const float* xcw  = (const float*)d_in[6];
    const float* dtw  = (const float*)d_in[7];
    const float* dtb  = (const float*)d_in[8];
    const float* alog = (const float*)d_in[9];
    const float* Dp   = (const float*)d_in[10];
    const float* Wop  = (const float*)d_in[11];
    float* out = (float*)d_out;

    // workspace layout (floats) — ~109.5 MB
    float* ws   = (float*)d_ws;
    float* xz   = ws;                                // L*2*DI      = 12,582,912
    float* xcv  = xz   + (size_t)L * 2 * DI;         // L*DI        =  6,291,456
    float* dtbc = xcv  + (size_t)L * DI;             // L*NCOMB     =    327,680
    float* dty  = dtbc + (size_t)L * NCOMB;          // L*DI (dt)   =  6,291,456
    float* Wt   = dty  + (size_t)L * DI;             // DI*NCOMB    =    122,880
    u16*   hc   = (u16*)(Wt + (size_t)DI * NCOMB);   // NC*DI*DS u16=  1,572,864 fl
    float* Ssum = Wt + (size_t)DI * NCOMB
                     + (size_t)NC * DI * DS / 2;     // NC*DI       =    196,608

    // aliases into regions dead at time of use
    u16*   ubf  = (u16*)xcv;                   // [4096][768]  (dead after GEMM1)
    u16*   Wipb = (u16*)xcv + (size_t)L * DM;  // [3072][768]  (dead after GEMM1)
    float* g2p  = dty;                         // [16][4096][80] (dead after reduce)
    u16*   xzu  = (u16*)xz;                    // x-half of xz rows: ybf + wopb

    const dim3 blk(256);

    // 1) early packs
    pack_early_k<<<(NU4 + NW4 + NWT + 255) / 256, blk, 0, stream>>>(
        u, Wip, xdt, xbw, xcw, ubf, Wipb, Wt);

    // 2) xz = u @ in_proj_w^T   [4096, 3072]  (bf16 MFMA, K=768)
    gemm_bf16_bt<<<dim3((2 * DI) / 128, L / 128), blk, 0, stream>>>(
        ubf, Wipb, xz, L, 2 * DI, DM);

    // 3) causal conv + SiLU -> xcv
    conv_silu_v4<<<(L * (DI / 4) + 255) / 256, blk, 0, stream>>>(xz, cw, cb, xcv);

    // 4) Wop -> bf16 into dead x-half of xz
    pack_wop_k<<<(NO4 + 255) / 256, blk, 0, stream>>>(Wop, xzu);

    // 5) [dt_rank|B|C] = xcv @ Wt via split-K
    gemm2_splitk<<<dim3(L / 64, G2_S), blk, 0, stream>>>(xcv, Wt, g2p);
    gemm2_reduce<<<(L * NCOMB + 255) / 256, blk, 0, stream>>>(g2p, dtbc);

    // 6) dt = softplus(dtr @ dtw^T + dtb)  (overwrites g2p region)
    dt_k<<<dim3(DI / 256, L / 32), blk, 0, stream>>>(dtbc, dtw, dtb, dty);

    // 7-9) chunked selective scan (CH=32, 128 chunks)
    scan1_k<<<dim3(DI / 256, NC), blk, 0, stream>>>(dty, xcv, dtbc, alog, hc, Ssum);
    scan2_k<<<(DI * DS) / 256, blk, 0, stream>>>(hc, Ssum, alog);
    scan3_k<<<dim3(DI / 256, NC), blk, 0, stream>>>(
        dty, xcv, dtbc, alog, hc, Dp, xz, xzu);

    // 10) out = yz @ out_proj_w^T   [4096, 768]  (bf16 MFMA, strided rows)
    gemm_bf16_bt_n64<<<dim3(DM / 64, L / 128), blk, 0, stream>>>(
        xzu, XZROW, xzu + 1536, XZROW, out, L, DM, DI);
}